// Round 1
// baseline (1813.893 us; speedup 1.0000x reference)
//
#include <hip/hip_runtime.h>
#include <cstdint>
#include <cstddef>
#include <cmath>

// DiffusionActiveInference on MI355X (gfx950).
// Strategy: batch the 16 independent trajectories -> M=16384 row GEMMs,
// sequential over 5 horizon steps. All matmuls via mfma_f32_16x16x32_bf16
// with the verified m97 structure (128x128 tile, BK=32, global_load_lds
// width=16, B^T operand so both fragments are contiguous ds_read_b128).
// fp32 master copy of z avoids bf16 drift across steps.

typedef __bf16 bf16;
typedef __attribute__((ext_vector_type(8))) __bf16 bf16x8;
typedef __attribute__((ext_vector_type(4))) float f32x4;

static constexpr int BATCH = 1024, NTRAJ = 16, HORIZON = 5;
static constexpr int MR = NTRAJ * BATCH;  // 16384 GEMM rows
static constexpr float ENT_C = 1.4189385332046727f;  // 0.5*(1+log(2*pi))

// ---- async global->LDS, 16B per lane ----------------------------------
// LDS dest must be wave-uniform base; lane lands at base + lane*16.
__device__ __forceinline__ void gld_lds16(const bf16* g, const bf16* l) {
  typedef __attribute__((address_space(1))) const uint32_t gq_t;
  typedef __attribute__((address_space(3))) uint32_t lq_t;
  gq_t* gp = (gq_t*)(uintptr_t)g;                 // generic->AS1 via inttoptr
  lq_t* lp = (lq_t*)(uint32_t)(uintptr_t)l;       // generic LDS low 32 bits = offset
  __builtin_amdgcn_global_load_lds(gp, lp, 16, 0, 0);
}

// ---- generic GEMM: C = act(A[M,K](lda) @ Bt[N,K]^T + bias) ------------
// grid = (M/128, N/128), block = 256 (4 waves, each 64x64 = 4x4 MFMA tiles)
template <int ACT, int OUTF32>
__global__ __launch_bounds__(256) void gemm128(
    const bf16* __restrict__ A, int lda, int K, const bf16* __restrict__ Bt,
    const float* __restrict__ bias, void* __restrict__ Cout, int ldc) {
  __shared__ alignas(16) bf16 As[128 * 32];
  __shared__ alignas(16) bf16 Bs[128 * 32];
  const int tid = threadIdx.x;
  const int wave = tid >> 6, lane = tid & 63;
  const int quad = lane >> 4, l16 = lane & 15;
  const int rowBlk = blockIdx.x * 128, colBlk = blockIdx.y * 128;
  const int wr = wave >> 1, wc = wave & 1;

  // staging: wave stages 32 A-rows + 32 B-rows (2 issues each, 16 rows/issue)
  const int srow = lane >> 2;        // row within 16-row issue (4 lanes/row)
  const int skel = (lane & 3) * 8;   // k-element offset (8 bf16 = 16B)
  const bf16* gA0 = A + (size_t)(rowBlk + wave * 32 + srow) * lda + skel;
  const bf16* gA1 = A + (size_t)(rowBlk + wave * 32 + 16 + srow) * lda + skel;
  const bf16* gB0 = Bt + (size_t)(colBlk + wave * 32 + srow) * K + skel;
  const bf16* gB1 = Bt + (size_t)(colBlk + wave * 32 + 16 + srow) * K + skel;
  bf16* lA0 = As + (wave * 32) * 32;       // wave-uniform LDS bases
  bf16* lA1 = As + (wave * 32 + 16) * 32;
  bf16* lB0 = Bs + (wave * 32) * 32;
  bf16* lB1 = Bs + (wave * 32 + 16) * 32;

  // fragment read bases: A[m=l16][k=quad*8+j], B^T[n=l16][k=quad*8+j]
  const bf16* aRd = As + (size_t)(wr * 64 + l16) * 32 + quad * 8;
  const bf16* bRd = Bs + (size_t)(wc * 64 + l16) * 32 + quad * 8;

  f32x4 acc[4][4] = {};
  for (int k0 = 0; k0 < K; k0 += 32) {
    gld_lds16(gA0 + k0, lA0);
    gld_lds16(gA1 + k0, lA1);
    gld_lds16(gB0 + k0, lB0);
    gld_lds16(gB1 + k0, lB1);
    __syncthreads();  // drains vmcnt before barrier (compiler-inserted)
    bf16x8 af[4], bfr[4];
#pragma unroll
    for (int i = 0; i < 4; ++i) af[i] = *(const bf16x8*)(aRd + i * 16 * 32);
#pragma unroll
    for (int i = 0; i < 4; ++i) bfr[i] = *(const bf16x8*)(bRd + i * 16 * 32);
#pragma unroll
    for (int mi = 0; mi < 4; ++mi)
#pragma unroll
      for (int ni = 0; ni < 4; ++ni)
        acc[mi][ni] = __builtin_amdgcn_mfma_f32_16x16x32_bf16(
            af[mi], bfr[ni], acc[mi][ni], 0, 0, 0);
    __syncthreads();
  }

  // epilogue: D[row=quad*4+r][col=l16] per 16x16 tile (verified C/D mapping)
#pragma unroll
  for (int ni = 0; ni < 4; ++ni) {
    const int col = colBlk + wc * 64 + ni * 16 + l16;
    const float bb = bias[col];
#pragma unroll
    for (int mi = 0; mi < 4; ++mi) {
      const int row0 = rowBlk + wr * 64 + mi * 16 + quad * 4;
#pragma unroll
      for (int r = 0; r < 4; ++r) {
        float v = acc[mi][ni][r] + bb;
        if (ACT) v = v / (1.f + __expf(-v));  // silu
        if (OUTF32)
          ((float*)Cout)[(size_t)(row0 + r) * ldc + col] = v;
        else
          ((bf16*)Cout)[(size_t)(row0 + r) * ldc + col] = (bf16)v;
      }
    }
  }
}

// ---- heads: [mean|log_std] = H2 @ Wt^T; action->Zb, entropy->efe ------
// grid = (M/128), block 256. Wave w: rows w*32..+32, all 64 cols.
__global__ __launch_bounds__(256) void heads_kernel(
    const bf16* __restrict__ H, const bf16* __restrict__ Wt,
    const float* __restrict__ pbm, const float* __restrict__ pbs,
    const float* __restrict__ noise, bf16* __restrict__ Zb,
    float* __restrict__ efe, int t, float disc) {
  __shared__ alignas(16) bf16 As[128 * 32];
  __shared__ alignas(16) bf16 Bs[64 * 32];
  const int tid = threadIdx.x;
  const int wave = tid >> 6, lane = tid & 63;
  const int quad = lane >> 4, l16 = lane & 15;
  const int rowBlk = blockIdx.x * 128;

  const int srow = lane >> 2;
  const int skel = (lane & 3) * 8;
  const bf16* gA0 = H + (size_t)(rowBlk + wave * 32 + srow) * 1024 + skel;
  const bf16* gA1 = H + (size_t)(rowBlk + wave * 32 + 16 + srow) * 1024 + skel;
  const bf16* gB0 = Wt + (size_t)(wave * 16 + srow) * 1024 + skel;
  bf16* lA0 = As + (wave * 32) * 32;
  bf16* lA1 = As + (wave * 32 + 16) * 32;
  bf16* lB0 = Bs + (wave * 16) * 32;

  const bf16* aRd = As + (size_t)(wave * 32 + l16) * 32 + quad * 8;
  const bf16* bRd = Bs + (size_t)l16 * 32 + quad * 8;

  f32x4 acc[2][4] = {};
  for (int k0 = 0; k0 < 1024; k0 += 32) {
    gld_lds16(gA0 + k0, lA0);
    gld_lds16(gA1 + k0, lA1);
    gld_lds16(gB0 + k0, lB0);
    __syncthreads();
    bf16x8 af[2], bfr[4];
#pragma unroll
    for (int i = 0; i < 2; ++i) af[i] = *(const bf16x8*)(aRd + i * 16 * 32);
#pragma unroll
    for (int i = 0; i < 4; ++i) bfr[i] = *(const bf16x8*)(bRd + i * 16 * 32);
#pragma unroll
    for (int mi = 0; mi < 2; ++mi)
#pragma unroll
      for (int ni = 0; ni < 4; ++ni)
        acc[mi][ni] = __builtin_amdgcn_mfma_f32_16x16x32_bf16(
            af[mi], bfr[ni], acc[mi][ni], 0, 0, 0);
    __syncthreads();
  }

  // cols 0..31 = mean (ni 0,1); cols 32..63 = log_std (ni 2,3); same lane.
  float entacc[2][4];
#pragma unroll
  for (int mi = 0; mi < 2; ++mi)
#pragma unroll
    for (int r = 0; r < 4; ++r) entacc[mi][r] = 0.f;

#pragma unroll
  for (int mi = 0; mi < 2; ++mi) {
#pragma unroll
    for (int ni = 0; ni < 2; ++ni) {
      const int col = ni * 16 + l16;  // action dim 0..31
      const float bm = pbm[col], bs = pbs[col];
#pragma unroll
      for (int r = 0; r < 4; ++r) {
        const int row = rowBlk + wave * 32 + mi * 16 + quad * 4 + r;
        const int n = row >> 10, b = row & 1023;
        const float mean = acc[mi][ni][r] + bm;
        float ls = acc[mi][ni + 2][r] + bs;
        ls = fminf(fmaxf(ls, -5.f), 2.f);
        const float ep = noise[((n * 5 + t) * 1024 + b) * 32 + col];
        const float a = mean + __expf(ls) * ep;
        Zb[(size_t)row * 288 + 256 + col] = (bf16)a;
        entacc[mi][r] += ENT_C + ls;
      }
    }
  }
  // reduce entropy across the 16 lanes holding the same row
#pragma unroll
  for (int mi = 0; mi < 2; ++mi) {
#pragma unroll
    for (int r = 0; r < 4; ++r) {
      float e = entacc[mi][r];
      e += __shfl_xor(e, 1);
      e += __shfl_xor(e, 2);
      e += __shfl_xor(e, 4);
      e += __shfl_xor(e, 8);
      if (l16 == 0) {
        const int row = rowBlk + wave * 32 + mi * 16 + quad * 4 + r;
        efe[row] += disc * (-0.1f) * e;  // CONS_W * (-ent), discounted
      }
    }
  }
}

// ---- block-wide sum over 256 threads ----------------------------------
__device__ __forceinline__ float block_sum256(float v, float* red) {
#pragma unroll
  for (int m = 1; m < 64; m <<= 1) v += __shfl_xor(v, m);
  const int wave = threadIdx.x >> 6;
  if ((threadIdx.x & 63) == 0) red[wave] = v;
  __syncthreads();
  const float s = red[0] + red[1] + red[2] + red[3];
  __syncthreads();
  return s;
}

// ---- per-row: z_next, KL on normalized latents, epistemic -------------
// grid = (M), block 256 (one thread per latent dim)
__global__ __launch_bounds__(256) void step_finish(
    float* __restrict__ Zf, const float* __restrict__ delta,
    bf16* __restrict__ Zbn, float* __restrict__ efe, float disc) {
  __shared__ float red[4];
  const int m = blockIdx.x, c = threadIdx.x;
  const float z = Zf[(size_t)m * 256 + c];
  const float zn = z + delta[(size_t)m * 256 + c];
  const float s1 = block_sum256(z * z, red);
  const float s2 = block_sum256(zn * zn, red);
  const float inz = 1.f / (sqrtf(s1) + 1e-8f);
  const float inn = 1.f / (sqrtf(s2) + 1e-8f);
  const float d = z * inz - zn * inn;
  const float s3 = block_sum256(d * d, red);
  if (c == 0) efe[m] += disc * log1pf(0.5f * s3);
  Zf[(size_t)m * 256 + c] = zn;
  Zbn[(size_t)m * 288 + c] = (bf16)zn;
}

// ---- value head: efe += disc * (V2 . vW3 + vb3) -----------------------
// grid = (M/4), block 256: one wave per row, 16 elems/lane
__global__ __launch_bounds__(256) void value3_kernel(
    const bf16* __restrict__ V2, const float* __restrict__ vW3,
    const float* __restrict__ vb3, float* __restrict__ efe, float disc) {
  const int wave = threadIdx.x >> 6, lane = threadIdx.x & 63;
  const int m = blockIdx.x * 4 + wave;
  const bf16* h = V2 + (size_t)m * 1024 + lane * 16;
  const float* wv = vW3 + lane * 16;
  float s = 0.f;
#pragma unroll
  for (int i = 0; i < 16; ++i) s += (float)h[i] * wv[i];
#pragma unroll
  for (int msk = 1; msk < 64; msk <<= 1) s += __shfl_xor(s, msk);
  if (lane == 0) efe[m] += disc * (s + vb3[0]);
}

// ---- setup kernels ----------------------------------------------------
// out[n*K + k] = (bf16) in[k*ldin + n]   (weight transpose + cast)
__global__ void transpose_bf16(const float* __restrict__ in,
                               bf16* __restrict__ out, int K, int N, int ldin) {
  const int idx = blockIdx.x * 256 + threadIdx.x;
  if (idx >= K * N) return;
  const int n = idx / K, k = idx - n * K;
  out[idx] = (bf16)in[(size_t)k * ldin + n];
}

// combined [mean|log_std] head weights, transposed: [64,1024]
__global__ void combine_heads(const float* __restrict__ pWm,
                              const float* __restrict__ pWs,
                              bf16* __restrict__ out) {
  const int idx = blockIdx.x * 256 + threadIdx.x;  // 64*1024
  const int n = idx >> 10, k = idx & 1023;
  const float v = (n < 32) ? pWm[k * 32 + n] : pWs[k * 32 + (n - 32)];
  out[idx] = (bf16)v;
}

// vbias[t][j] = vb1[j] + time_embed(t) @ vW1[256:,:]  (row-uniform fold)
__global__ void make_vbias(const float* __restrict__ vW1,
                           const float* __restrict__ vb1,
                           float* __restrict__ vbias) {
  const int idx = blockIdx.x * 256 + threadIdx.x;
  if (idx >= 5 * 1024) return;
  const int t = idx >> 10, j = idx & 1023;
  float s = vb1[j];
  const float lt = (float)t;
  for (int i = 0; i < 64; ++i) {
    const float f = expf(-9.210340371976184f * (float)i / 64.f);
    const float ang = lt * f;
    s += sinf(ang) * vW1[(size_t)(256 + i) * 1024 + j];
    s += cosf(ang) * vW1[(size_t)(256 + 64 + i) * 1024 + j];
  }
  vbias[idx] = s;
}

// replicate latent across trajectories; zero efe accumulator
__global__ void init_state(const float* __restrict__ latent,
                           float* __restrict__ Zf, bf16* __restrict__ Zb,
                           float* __restrict__ efe) {
  const int idx = blockIdx.x * 256 + threadIdx.x;  // M*256
  const int m = idx >> 8, c = idx & 255;
  const int b = m & 1023;
  const float z = latent[(size_t)b * 256 + c];
  Zf[idx] = z;
  Zb[(size_t)m * 288 + c] = (bf16)z;
  if (c == 0) efe[m] = 0.f;
}

// out[b] = mean over 16 trajectories of efe[n*1024+b]
__global__ void finalize(const float* __restrict__ efe,
                         float* __restrict__ out) {
  const int b = blockIdx.x * 256 + threadIdx.x;  // 1024
  float s = 0.f;
#pragma unroll
  for (int n = 0; n < 16; ++n) s += efe[n * 1024 + b];
  out[b] = s * (1.f / 16.f);
}

extern "C" void kernel_launch(void* const* d_in, const int* in_sizes, int n_in,
                              void* d_out, int out_size, void* d_ws,
                              size_t ws_size, hipStream_t stream) {
  const float* latent = (const float*)d_in[0];
  const float* noise = (const float*)d_in[1];
  const float* pW1 = (const float*)d_in[2];
  const float* pb1 = (const float*)d_in[3];
  const float* pW2 = (const float*)d_in[4];
  const float* pb2 = (const float*)d_in[5];
  const float* pWm = (const float*)d_in[6];
  const float* pbm = (const float*)d_in[7];
  const float* pWs = (const float*)d_in[8];
  const float* pbs = (const float*)d_in[9];
  const float* dW1 = (const float*)d_in[10];
  const float* db1 = (const float*)d_in[11];
  const float* dW2 = (const float*)d_in[12];
  const float* db2 = (const float*)d_in[13];
  const float* dW3 = (const float*)d_in[14];
  const float* db3 = (const float*)d_in[15];
  const float* vW1 = (const float*)d_in[16];
  const float* vb1 = (const float*)d_in[17];
  const float* vW2 = (const float*)d_in[18];
  const float* vb2 = (const float*)d_in[19];
  const float* vW3 = (const float*)d_in[20];
  const float* vb3 = (const float*)d_in[21];

  char* w = (char*)d_ws;
  size_t off = 0;
  auto take = [&](size_t bytes) -> void* {
    void* p = (void*)(w + off);
    off = (off + bytes + 255) & ~(size_t)255;
    return p;
  };
  bf16* pW1t = (bf16*)take(1024ull * 256 * 2);   // [1024][256]
  bf16* pW2t = (bf16*)take(1024ull * 1024 * 2);  // [1024][1024]
  bf16* pHt = (bf16*)take(64ull * 1024 * 2);     // [64][1024] mean|log_std
  bf16* dW1t = (bf16*)take(1024ull * 288 * 2);   // [1024][288]
  bf16* dW2t = (bf16*)take(1024ull * 1024 * 2);
  bf16* dW3t = (bf16*)take(256ull * 1024 * 2);   // [256][1024]
  bf16* vW1t = (bf16*)take(1024ull * 256 * 2);   // [1024][256] (z part only)
  bf16* vW2t = (bf16*)take(1024ull * 1024 * 2);
  float* vbias = (float*)take(5ull * 1024 * 4);  // per-step value-l1 bias
  bf16* Zb0 = (bf16*)take((size_t)MR * 288 * 2); // [M][288] = z | action
  bf16* Zb1 = (bf16*)take((size_t)MR * 288 * 2);
  float* Zf = (float*)take((size_t)MR * 256 * 4);  // fp32 master z
  bf16* Ha = (bf16*)take((size_t)MR * 1024 * 2);
  bf16* Hb = (bf16*)take((size_t)MR * 1024 * 2);
  float* efe = (float*)take((size_t)MR * 4);
  float* delta = (float*)Ha;  // f32 [M,256] aliases Ha; lifetimes disjoint

  const dim3 blk(256);
  // ---- setup: weight transposes (fp32 -> bf16, [N,K]) ----
  transpose_bf16<<<dim3(256 * 1024 / 256), blk, 0, stream>>>(pW1, pW1t, 256, 1024, 1024);
  transpose_bf16<<<dim3(1024 * 1024 / 256), blk, 0, stream>>>(pW2, pW2t, 1024, 1024, 1024);
  combine_heads<<<dim3(64 * 1024 / 256), blk, 0, stream>>>(pWm, pWs, pHt);
  transpose_bf16<<<dim3(288 * 1024 / 256), blk, 0, stream>>>(dW1, dW1t, 288, 1024, 1024);
  transpose_bf16<<<dim3(1024 * 1024 / 256), blk, 0, stream>>>(dW2, dW2t, 1024, 1024, 1024);
  transpose_bf16<<<dim3(1024 * 256 / 256), blk, 0, stream>>>(dW3, dW3t, 1024, 256, 256);
  transpose_bf16<<<dim3(256 * 1024 / 256), blk, 0, stream>>>(vW1, vW1t, 256, 1024, 1024);
  transpose_bf16<<<dim3(1024 * 1024 / 256), blk, 0, stream>>>(vW2, vW2t, 1024, 1024, 1024);
  make_vbias<<<dim3(20), blk, 0, stream>>>(vW1, vb1, vbias);
  init_state<<<dim3(MR), blk, 0, stream>>>(latent, Zf, Zb0, efe);

  // ---- 5 horizon steps, 16 trajectories batched as M=16384 ----
  for (int t = 0; t < HORIZON; ++t) {
    bf16* Zc = (t & 1) ? Zb1 : Zb0;
    bf16* Zn = (t & 1) ? Zb0 : Zb1;
    const float disc = (float)pow(0.99, (double)t);
    // policy trunk
    gemm128<1, 0><<<dim3(128, 8), blk, 0, stream>>>(Zc, 288, 256, pW1t, pb1, Ha, 1024);
    gemm128<1, 0><<<dim3(128, 8), blk, 0, stream>>>(Ha, 1024, 1024, pW2t, pb2, Hb, 1024);
    // heads: action -> Zc[:,256:288], entropy -> efe
    heads_kernel<<<dim3(128), blk, 0, stream>>>(Hb, pHt, pbm, pbs, noise, Zc, efe, t, disc);
    // dynamics on [z|action]
    gemm128<1, 0><<<dim3(128, 8), blk, 0, stream>>>(Zc, 288, 288, dW1t, db1, Ha, 1024);
    gemm128<1, 0><<<dim3(128, 8), blk, 0, stream>>>(Ha, 1024, 1024, dW2t, db2, Hb, 1024);
    gemm128<0, 1><<<dim3(128, 2), blk, 0, stream>>>(Hb, 1024, 1024, dW3t, db3, delta, 256);
    // z_next, KL, epistemic
    step_finish<<<dim3(MR), blk, 0, stream>>>(Zf, delta, Zn, efe, disc);
    // value on z_next (time-embed folded into vbias[t])
    gemm128<1, 0><<<dim3(128, 8), blk, 0, stream>>>(Zn, 288, 256, vW1t, vbias + t * 1024, Ha, 1024);
    gemm128<1, 0><<<dim3(128, 8), blk, 0, stream>>>(Ha, 1024, 1024, vW2t, vb2, Hb, 1024);
    value3_kernel<<<dim3(MR / 4), blk, 0, stream>>>(Hb, vW3, vb3, efe, disc);
  }
  finalize<<<dim3(4), blk, 0, stream>>>(efe, (float*)d_out);
}

// Round 2
// 1754.384 us; speedup vs baseline: 1.0339x; 1.0339x over previous
//
#include <hip/hip_runtime.h>
#include <cstdint>
#include <cstddef>
#include <cmath>

// DiffusionActiveInference on MI355X (gfx950).
// R1: operand-swapped MFMA epilogue (lane holds 4 consecutive COLS of one row
// -> bf16x4/float4 packed stores, 16 stores/thread instead of 64 ushort),
// heads_kernel re-gridded to 256 blocks, step_finish wave-per-row (no
// barriers), value3 vectorized. K-loop structure (m97: 128x128 tile, BK=32,
// global_load_lds width=16) unchanged.

typedef __bf16 bf16;
typedef __attribute__((ext_vector_type(8))) __bf16 bf16x8;
typedef __attribute__((ext_vector_type(4))) __bf16 bf16x4;
typedef __attribute__((ext_vector_type(4))) float f32x4;

static constexpr int BATCH = 1024, NTRAJ = 16, HORIZON = 5;
static constexpr int MR = NTRAJ * BATCH;  // 16384 GEMM rows
static constexpr float ENT_C = 1.4189385332046727f;  // 0.5*(1+log(2*pi))

// ---- async global->LDS, 16B per lane ----------------------------------
__device__ __forceinline__ void gld_lds16(const bf16* g, const bf16* l) {
  typedef __attribute__((address_space(1))) const uint32_t gq_t;
  typedef __attribute__((address_space(3))) uint32_t lq_t;
  gq_t* gp = (gq_t*)(uintptr_t)g;
  lq_t* lp = (lq_t*)(uint32_t)(uintptr_t)l;
  __builtin_amdgcn_global_load_lds(gp, lp, 16, 0, 0);
}

__device__ __forceinline__ float silu(float x) {
  return x / (1.f + __expf(-x));
}

// ---- generic GEMM: C = act(A[M,K](lda) @ Bt[N,K]^T + bias) ------------
// grid = (M/128, N/128), block = 256 (4 waves, each 64x64 = 4x4 MFMA tiles)
// MFMA operands SWAPPED so D[M'=col][N'=row]: lane l16 = row, quad*4+r = col
// -> each lane's 4 acc regs are 4 consecutive cols of one row (packed store).
template <int ACT, int OUTF32>
__global__ __launch_bounds__(256) void gemm128(
    const bf16* __restrict__ A, int lda, int K, const bf16* __restrict__ Bt,
    const float* __restrict__ bias, void* __restrict__ Cout, int ldc) {
  __shared__ alignas(16) bf16 As[128 * 32];
  __shared__ alignas(16) bf16 Bs[128 * 32];
  const int tid = threadIdx.x;
  const int wave = tid >> 6, lane = tid & 63;
  const int quad = lane >> 4, l16 = lane & 15;
  const int rowBlk = blockIdx.x * 128, colBlk = blockIdx.y * 128;
  const int wr = wave >> 1, wc = wave & 1;

  const int srow = lane >> 2;        // row within 16-row issue (4 lanes/row)
  const int skel = (lane & 3) * 8;   // k-element offset (8 bf16 = 16B)
  const bf16* gA0 = A + (size_t)(rowBlk + wave * 32 + srow) * lda + skel;
  const bf16* gA1 = A + (size_t)(rowBlk + wave * 32 + 16 + srow) * lda + skel;
  const bf16* gB0 = Bt + (size_t)(colBlk + wave * 32 + srow) * K + skel;
  const bf16* gB1 = Bt + (size_t)(colBlk + wave * 32 + 16 + srow) * K + skel;
  bf16* lA0 = As + (wave * 32) * 32;
  bf16* lA1 = As + (wave * 32 + 16) * 32;
  bf16* lB0 = Bs + (wave * 32) * 32;
  bf16* lB1 = Bs + (wave * 32 + 16) * 32;

  const bf16* aRd = As + (size_t)(wr * 64 + l16) * 32 + quad * 8;
  const bf16* bRd = Bs + (size_t)(wc * 64 + l16) * 32 + quad * 8;

  f32x4 acc[4][4] = {};
  for (int k0 = 0; k0 < K; k0 += 32) {
    gld_lds16(gA0 + k0, lA0);
    gld_lds16(gA1 + k0, lA1);
    gld_lds16(gB0 + k0, lB0);
    gld_lds16(gB1 + k0, lB1);
    __syncthreads();
    bf16x8 af[4], bfr[4];
#pragma unroll
    for (int i = 0; i < 4; ++i) af[i] = *(const bf16x8*)(aRd + i * 16 * 32);
#pragma unroll
    for (int i = 0; i < 4; ++i) bfr[i] = *(const bf16x8*)(bRd + i * 16 * 32);
#pragma unroll
    for (int mi = 0; mi < 4; ++mi)
#pragma unroll
      for (int ni = 0; ni < 4; ++ni)
        acc[mi][ni] = __builtin_amdgcn_mfma_f32_16x16x32_bf16(
            bfr[ni], af[mi], acc[mi][ni], 0, 0, 0);  // swapped operands
    __syncthreads();
  }

  // epilogue: row = ...+l16 (N' of swapped D), col0 = ...+quad*4 (M')
#pragma unroll
  for (int mi = 0; mi < 4; ++mi) {
    const int row = rowBlk + wr * 64 + mi * 16 + l16;
#pragma unroll
    for (int ni = 0; ni < 4; ++ni) {
      const int col0 = colBlk + wc * 64 + ni * 16 + quad * 4;
      const f32x4 bb = *(const f32x4*)(bias + col0);
      float v[4];
#pragma unroll
      for (int r = 0; r < 4; ++r) {
        float x = acc[mi][ni][r] + bb[r];
        if (ACT) x = silu(x);
        v[r] = x;
      }
      if (OUTF32) {
        f32x4 o = {v[0], v[1], v[2], v[3]};
        *(f32x4*)((float*)Cout + (size_t)row * ldc + col0) = o;
      } else {
        bf16x4 o = {(bf16)v[0], (bf16)v[1], (bf16)v[2], (bf16)v[3]};
        *(bf16x4*)((bf16*)Cout + (size_t)row * ldc + col0) = o;
      }
    }
  }
}

// ---- heads: [mean|log_std] = H2 @ Wt^T; action->Zb, entropy->efe ------
// grid = (M/64), block 256. Wave w: rows w*16..+16, all 64 cols.
__global__ __launch_bounds__(256) void heads_kernel(
    const bf16* __restrict__ H, const bf16* __restrict__ Wt,
    const float* __restrict__ pbm, const float* __restrict__ pbs,
    const float* __restrict__ noise, bf16* __restrict__ Zb,
    float* __restrict__ efe, int t, float disc) {
  __shared__ alignas(16) bf16 As[64 * 32];
  __shared__ alignas(16) bf16 Bs[64 * 32];
  const int tid = threadIdx.x;
  const int wave = tid >> 6, lane = tid & 63;
  const int quad = lane >> 4, l16 = lane & 15;
  const int rowBlk = blockIdx.x * 64;

  const int srow = lane >> 2;
  const int skel = (lane & 3) * 8;
  const bf16* gA = H + (size_t)(rowBlk + wave * 16 + srow) * 1024 + skel;
  const bf16* gB = Wt + (size_t)(wave * 16 + srow) * 1024 + skel;
  bf16* lA = As + (wave * 16) * 32;
  bf16* lB = Bs + (wave * 16) * 32;

  const bf16* aRd = As + (size_t)(wave * 16 + l16) * 32 + quad * 8;
  const bf16* bRd = Bs + (size_t)l16 * 32 + quad * 8;

  f32x4 acc[4] = {};
  for (int k0 = 0; k0 < 1024; k0 += 32) {
    gld_lds16(gA + k0, lA);
    gld_lds16(gB + k0, lB);
    __syncthreads();
    bf16x8 af = *(const bf16x8*)aRd;
    bf16x8 bfr[4];
#pragma unroll
    for (int i = 0; i < 4; ++i) bfr[i] = *(const bf16x8*)(bRd + i * 16 * 32);
#pragma unroll
    for (int ni = 0; ni < 4; ++ni)
      acc[ni] = __builtin_amdgcn_mfma_f32_16x16x32_bf16(bfr[ni], af, acc[ni],
                                                        0, 0, 0);  // swapped
    __syncthreads();
  }

  // lane: row = rowBlk + wave*16 + l16; cols ni*16 + quad*4 + r
  // ni 0,1 = mean cols 0..31; ni 2,3 = log_std cols 32..63 (paired)
  const int row = rowBlk + wave * 16 + l16;
  const int n = row >> 10, b = row & 1023;
  float ent = 0.f;
#pragma unroll
  for (int ni = 0; ni < 2; ++ni) {
    const int col0 = ni * 16 + quad * 4;
    const f32x4 bm4 = *(const f32x4*)(pbm + col0);
    const f32x4 bs4 = *(const f32x4*)(pbs + col0);
    const f32x4 ep4 = *(const f32x4*)(noise + (((size_t)(n * 5 + t) * 1024 + b) * 32 + col0));
    bf16x4 o;
#pragma unroll
    for (int r = 0; r < 4; ++r) {
      const float mean = acc[ni][r] + bm4[r];
      float ls = acc[ni + 2][r] + bs4[r];
      ls = fminf(fmaxf(ls, -5.f), 2.f);
      o[r] = (bf16)(mean + __expf(ls) * ep4[r]);
      ent += ENT_C + ls;
    }
    *(bf16x4*)(Zb + (size_t)row * 288 + 256 + col0) = o;
  }
  // sum over the 4 quads holding this row's 32 action cols
  ent += __shfl_xor(ent, 16);
  ent += __shfl_xor(ent, 32);
  if (quad == 0) efe[row] += disc * (-0.1f) * ent;
}

// ---- per-row: z_next, KL on normalized latents, epistemic -------------
// grid = (M/4), block 256: one WAVE per row, 4 elems/lane, shuffle-only
__global__ __launch_bounds__(256) void step_finish(
    float* __restrict__ Zf, const float* __restrict__ delta,
    bf16* __restrict__ Zbn, float* __restrict__ efe, float disc) {
  const int wave = threadIdx.x >> 6, lane = threadIdx.x & 63;
  const int m = blockIdx.x * 4 + wave;
  float* zp = Zf + (size_t)m * 256 + lane * 4;
  const f32x4 z = *(const f32x4*)zp;
  const f32x4 d = *(const f32x4*)(delta + (size_t)m * 256 + lane * 4);
  f32x4 zn;
  float s1 = 0.f, s2 = 0.f;
#pragma unroll
  for (int r = 0; r < 4; ++r) {
    zn[r] = z[r] + d[r];
    s1 += z[r] * z[r];
    s2 += zn[r] * zn[r];
  }
#pragma unroll
  for (int msk = 1; msk < 64; msk <<= 1) {
    s1 += __shfl_xor(s1, msk);
    s2 += __shfl_xor(s2, msk);
  }
  const float inz = 1.f / (sqrtf(s1) + 1e-8f);
  const float inn = 1.f / (sqrtf(s2) + 1e-8f);
  float s3 = 0.f;
#pragma unroll
  for (int r = 0; r < 4; ++r) {
    const float df = z[r] * inz - zn[r] * inn;
    s3 += df * df;
  }
#pragma unroll
  for (int msk = 1; msk < 64; msk <<= 1) s3 += __shfl_xor(s3, msk);
  if (lane == 0) efe[m] += disc * log1pf(0.5f * s3);
  *(f32x4*)zp = zn;
  bf16x4 o = {(bf16)zn[0], (bf16)zn[1], (bf16)zn[2], (bf16)zn[3]};
  *(bf16x4*)(Zbn + (size_t)m * 288 + lane * 4) = o;
}

// ---- value head: efe += disc * (V2 . vW3 + vb3) -----------------------
// grid = (M/4), block 256: one wave per row, 16 elems/lane
__global__ __launch_bounds__(256) void value3_kernel(
    const bf16* __restrict__ V2, const float* __restrict__ vW3,
    const float* __restrict__ vb3, float* __restrict__ efe, float disc) {
  const int wave = threadIdx.x >> 6, lane = threadIdx.x & 63;
  const int m = blockIdx.x * 4 + wave;
  const bf16* h = V2 + (size_t)m * 1024 + lane * 16;
  const float* wv = vW3 + lane * 16;
  const bf16x8 ha = *(const bf16x8*)h;
  const bf16x8 hb = *(const bf16x8*)(h + 8);
  const f32x4 w0 = *(const f32x4*)wv;
  const f32x4 w1 = *(const f32x4*)(wv + 4);
  const f32x4 w2 = *(const f32x4*)(wv + 8);
  const f32x4 w3 = *(const f32x4*)(wv + 12);
  float s = 0.f;
#pragma unroll
  for (int r = 0; r < 4; ++r) {
    s += (float)ha[r] * w0[r] + (float)ha[r + 4] * w1[r];
    s += (float)hb[r] * w2[r] + (float)hb[r + 4] * w3[r];
  }
#pragma unroll
  for (int msk = 1; msk < 64; msk <<= 1) s += __shfl_xor(s, msk);
  if (lane == 0) efe[m] += disc * (s + vb3[0]);
}

// ---- setup kernels ----------------------------------------------------
__global__ void transpose_bf16(const float* __restrict__ in,
                               bf16* __restrict__ out, int K, int N, int ldin) {
  const int idx = blockIdx.x * 256 + threadIdx.x;
  if (idx >= K * N) return;
  const int n = idx / K, k = idx - n * K;
  out[idx] = (bf16)in[(size_t)k * ldin + n];
}

__global__ void combine_heads(const float* __restrict__ pWm,
                              const float* __restrict__ pWs,
                              bf16* __restrict__ out) {
  const int idx = blockIdx.x * 256 + threadIdx.x;  // 64*1024
  const int n = idx >> 10, k = idx & 1023;
  const float v = (n < 32) ? pWm[k * 32 + n] : pWs[k * 32 + (n - 32)];
  out[idx] = (bf16)v;
}

__global__ void make_vbias(const float* __restrict__ vW1,
                           const float* __restrict__ vb1,
                           float* __restrict__ vbias) {
  const int idx = blockIdx.x * 256 + threadIdx.x;
  if (idx >= 5 * 1024) return;
  const int t = idx >> 10, j = idx & 1023;
  float s = vb1[j];
  const float lt = (float)t;
  for (int i = 0; i < 64; ++i) {
    const float f = expf(-9.210340371976184f * (float)i / 64.f);
    const float ang = lt * f;
    s += sinf(ang) * vW1[(size_t)(256 + i) * 1024 + j];
    s += cosf(ang) * vW1[(size_t)(256 + 64 + i) * 1024 + j];
  }
  vbias[idx] = s;
}

__global__ void init_state(const float* __restrict__ latent,
                           float* __restrict__ Zf, bf16* __restrict__ Zb,
                           float* __restrict__ efe) {
  const int idx = blockIdx.x * 256 + threadIdx.x;  // M*256
  const int m = idx >> 8, c = idx & 255;
  const int b = m & 1023;
  const float z = latent[(size_t)b * 256 + c];
  Zf[idx] = z;
  Zb[(size_t)m * 288 + c] = (bf16)z;
  if (c == 0) efe[m] = 0.f;
}

__global__ void finalize(const float* __restrict__ efe,
                         float* __restrict__ out) {
  const int b = blockIdx.x * 256 + threadIdx.x;  // 1024
  float s = 0.f;
#pragma unroll
  for (int n = 0; n < 16; ++n) s += efe[n * 1024 + b];
  out[b] = s * (1.f / 16.f);
}

extern "C" void kernel_launch(void* const* d_in, const int* in_sizes, int n_in,
                              void* d_out, int out_size, void* d_ws,
                              size_t ws_size, hipStream_t stream) {
  const float* latent = (const float*)d_in[0];
  const float* noise = (const float*)d_in[1];
  const float* pW1 = (const float*)d_in[2];
  const float* pb1 = (const float*)d_in[3];
  const float* pW2 = (const float*)d_in[4];
  const float* pb2 = (const float*)d_in[5];
  const float* pWm = (const float*)d_in[6];
  const float* pbm = (const float*)d_in[7];
  const float* pWs = (const float*)d_in[8];
  const float* pbs = (const float*)d_in[9];
  const float* dW1 = (const float*)d_in[10];
  const float* db1 = (const float*)d_in[11];
  const float* dW2 = (const float*)d_in[12];
  const float* db2 = (const float*)d_in[13];
  const float* dW3 = (const float*)d_in[14];
  const float* db3 = (const float*)d_in[15];
  const float* vW1 = (const float*)d_in[16];
  const float* vb1 = (const float*)d_in[17];
  const float* vW2 = (const float*)d_in[18];
  const float* vb2 = (const float*)d_in[19];
  const float* vW3 = (const float*)d_in[20];
  const float* vb3 = (const float*)d_in[21];

  char* w = (char*)d_ws;
  size_t off = 0;
  auto take = [&](size_t bytes) -> void* {
    void* p = (void*)(w + off);
    off = (off + bytes + 255) & ~(size_t)255;
    return p;
  };
  bf16* pW1t = (bf16*)take(1024ull * 256 * 2);
  bf16* pW2t = (bf16*)take(1024ull * 1024 * 2);
  bf16* pHt = (bf16*)take(64ull * 1024 * 2);
  bf16* dW1t = (bf16*)take(1024ull * 288 * 2);
  bf16* dW2t = (bf16*)take(1024ull * 1024 * 2);
  bf16* dW3t = (bf16*)take(256ull * 1024 * 2);
  bf16* vW1t = (bf16*)take(1024ull * 256 * 2);
  bf16* vW2t = (bf16*)take(1024ull * 1024 * 2);
  float* vbias = (float*)take(5ull * 1024 * 4);
  bf16* Zb0 = (bf16*)take((size_t)MR * 288 * 2);
  bf16* Zb1 = (bf16*)take((size_t)MR * 288 * 2);
  float* Zf = (float*)take((size_t)MR * 256 * 4);
  bf16* Ha = (bf16*)take((size_t)MR * 1024 * 2);
  bf16* Hb = (bf16*)take((size_t)MR * 1024 * 2);
  float* efe = (float*)take((size_t)MR * 4);
  float* delta = (float*)Ha;  // f32 [M,256] aliases Ha; lifetimes disjoint

  const dim3 blk(256);
  transpose_bf16<<<dim3(256 * 1024 / 256), blk, 0, stream>>>(pW1, pW1t, 256, 1024, 1024);
  transpose_bf16<<<dim3(1024 * 1024 / 256), blk, 0, stream>>>(pW2, pW2t, 1024, 1024, 1024);
  combine_heads<<<dim3(64 * 1024 / 256), blk, 0, stream>>>(pWm, pWs, pHt);
  transpose_bf16<<<dim3(288 * 1024 / 256), blk, 0, stream>>>(dW1, dW1t, 288, 1024, 1024);
  transpose_bf16<<<dim3(1024 * 1024 / 256), blk, 0, stream>>>(dW2, dW2t, 1024, 1024, 1024);
  transpose_bf16<<<dim3(1024 * 256 / 256), blk, 0, stream>>>(dW3, dW3t, 1024, 256, 256);
  transpose_bf16<<<dim3(256 * 1024 / 256), blk, 0, stream>>>(vW1, vW1t, 256, 1024, 1024);
  transpose_bf16<<<dim3(1024 * 1024 / 256), blk, 0, stream>>>(vW2, vW2t, 1024, 1024, 1024);
  make_vbias<<<dim3(20), blk, 0, stream>>>(vW1, vb1, vbias);
  init_state<<<dim3(MR), blk, 0, stream>>>(latent, Zf, Zb0, efe);

  for (int t = 0; t < HORIZON; ++t) {
    bf16* Zc = (t & 1) ? Zb1 : Zb0;
    bf16* Zn = (t & 1) ? Zb0 : Zb1;
    const float disc = (float)pow(0.99, (double)t);
    // policy trunk
    gemm128<1, 0><<<dim3(128, 8), blk, 0, stream>>>(Zc, 288, 256, pW1t, pb1, Ha, 1024);
    gemm128<1, 0><<<dim3(128, 8), blk, 0, stream>>>(Ha, 1024, 1024, pW2t, pb2, Hb, 1024);
    // heads: action -> Zc[:,256:288], entropy -> efe
    heads_kernel<<<dim3(MR / 64), blk, 0, stream>>>(Hb, pHt, pbm, pbs, noise, Zc, efe, t, disc);
    // dynamics on [z|action]
    gemm128<1, 0><<<dim3(128, 8), blk, 0, stream>>>(Zc, 288, 288, dW1t, db1, Ha, 1024);
    gemm128<1, 0><<<dim3(128, 8), blk, 0, stream>>>(Ha, 1024, 1024, dW2t, db2, Hb, 1024);
    gemm128<0, 1><<<dim3(128, 2), blk, 0, stream>>>(Hb, 1024, 1024, dW3t, db3, delta, 256);
    // z_next, KL, epistemic
    step_finish<<<dim3(MR / 4), blk, 0, stream>>>(Zf, delta, Zn, efe, disc);
    // value on z_next (time-embed folded into vbias[t])
    gemm128<1, 0><<<dim3(128, 8), blk, 0, stream>>>(Zn, 288, 256, vW1t, vbias + t * 1024, Ha, 1024);
    gemm128<1, 0><<<dim3(128, 8), blk, 0, stream>>>(Ha, 1024, 1024, vW2t, vb2, Hb, 1024);
    value3_kernel<<<dim3(MR / 4), blk, 0, stream>>>(Hb, vW3, vb3, efe, disc);
  }
  finalize<<<dim3(4), blk, 0, stream>>>(efe, (float*)d_out);
}

// Round 3
// 1678.471 us; speedup vs baseline: 1.0807x; 1.0452x over previous
//
#include <hip/hip_runtime.h>
#include <cstdint>
#include <cstddef>
#include <cmath>

// DiffusionActiveInference on MI355X (gfx950).
// R3: (1) BK=64 K-loop as dual BK=32 LDS panels (half the barriers, same
// bank-friendly 64B row stride); (2) fusions: [pL1|dL1z] merged N=2048 GEMM,
// heads completes dynamics-L1 via rank-32 MFMA, dL3+step_finish fused
// (delta never materialized; KL from dot-product partials), value-L2 fused
// with the vW3 dot (no 32MB output); (3) Zb shrunk to [M,256].

typedef __bf16 bf16;
typedef __attribute__((ext_vector_type(8))) __bf16 bf16x8;
typedef __attribute__((ext_vector_type(4))) __bf16 bf16x4;
typedef __attribute__((ext_vector_type(4))) float f32x4;

static constexpr int BATCH = 1024, NTRAJ = 16, HORIZON = 5;
static constexpr int MR = NTRAJ * BATCH;  // 16384 GEMM rows
static constexpr float ENT_C = 1.4189385332046727f;  // 0.5*(1+log(2*pi))
static constexpr float SUMDISC = 4.90099501f;        // sum 0.99^t, t=0..4

// ---- async global->LDS, 16B per lane ----------------------------------
__device__ __forceinline__ void gld_lds16(const bf16* g, const bf16* l) {
  typedef __attribute__((address_space(1))) const uint32_t gq_t;
  typedef __attribute__((address_space(3))) uint32_t lq_t;
  gq_t* gp = (gq_t*)(uintptr_t)g;
  lq_t* lp = (lq_t*)(uint32_t)(uintptr_t)l;
  __builtin_amdgcn_global_load_lds(gp, lp, 16, 0, 0);
}

__device__ __forceinline__ float silu(float x) {
  return x / (1.f + __expf(-x));
}

#define MFMA16(a, b, c) __builtin_amdgcn_mfma_f32_16x16x32_bf16((a), (b), (c), 0, 0, 0)

// ---- generic GEMM: C = maybe_silu(A[M,K](lda) @ Bt[N,K]^T + bias) -----
// grid (M/128, N/128), block 256. BK=64 as two BK=32 panels.
// silu iff colBlk < act_cols; output goes to C1 if colBlk < act_cols else
// C2 at (col - act_cols). bf16 output.
__global__ __launch_bounds__(256) void gemm128(
    const bf16* __restrict__ A, int lda, int K, const bf16* __restrict__ Bt,
    const float* __restrict__ bias, int act_cols,
    bf16* __restrict__ C1, bf16* __restrict__ C2, int ldc) {
  __shared__ alignas(16) bf16 As0[128 * 32], As1[128 * 32];
  __shared__ alignas(16) bf16 Bs0[128 * 32], Bs1[128 * 32];
  const int tid = threadIdx.x, wave = tid >> 6, lane = tid & 63;
  const int quad = lane >> 4, l16 = lane & 15;
  const int rowBlk = blockIdx.x * 128, colBlk = blockIdx.y * 128;
  const int wr = wave >> 1, wc = wave & 1;
  const int srow = lane >> 2, skel = (lane & 3) * 8;

  const bf16* gA0 = A + (size_t)(rowBlk + wave * 32 + srow) * lda + skel;
  const bf16* gA1 = gA0 + (size_t)16 * lda;
  const bf16* gB0 = Bt + (size_t)(colBlk + wave * 32 + srow) * K + skel;
  const bf16* gB1 = gB0 + (size_t)16 * K;
  bf16* const lA0 = As0 + wave * 32 * 32;
  bf16* const lA0b = As0 + (wave * 32 + 16) * 32;
  bf16* const lA1 = As1 + wave * 32 * 32;
  bf16* const lA1b = As1 + (wave * 32 + 16) * 32;
  bf16* const lB0 = Bs0 + wave * 32 * 32;
  bf16* const lB0b = Bs0 + (wave * 32 + 16) * 32;
  bf16* const lB1 = Bs1 + wave * 32 * 32;
  bf16* const lB1b = Bs1 + (wave * 32 + 16) * 32;

  f32x4 acc[4][4] = {};
  for (int k0 = 0; k0 < K; k0 += 64) {
    gld_lds16(gA0 + k0, lA0);
    gld_lds16(gA1 + k0, lA0b);
    gld_lds16(gA0 + k0 + 32, lA1);
    gld_lds16(gA1 + k0 + 32, lA1b);
    gld_lds16(gB0 + k0, lB0);
    gld_lds16(gB1 + k0, lB0b);
    gld_lds16(gB0 + k0 + 32, lB1);
    gld_lds16(gB1 + k0 + 32, lB1b);
    __syncthreads();
#pragma unroll
    for (int ks = 0; ks < 2; ++ks) {
      const bf16* aRd = (ks ? As1 : As0) + (wr * 64 + l16) * 32 + quad * 8;
      const bf16* bRd = (ks ? Bs1 : Bs0) + (wc * 64 + l16) * 32 + quad * 8;
      bf16x8 af[4], bfr[4];
#pragma unroll
      for (int i = 0; i < 4; ++i) {
        af[i] = *(const bf16x8*)(aRd + i * 16 * 32);
        bfr[i] = *(const bf16x8*)(bRd + i * 16 * 32);
      }
#pragma unroll
      for (int mi = 0; mi < 4; ++mi)
#pragma unroll
        for (int ni = 0; ni < 4; ++ni)
          acc[mi][ni] = MFMA16(bfr[ni], af[mi], acc[mi][ni]);
    }
    __syncthreads();
  }

  // swapped-operand D: lane holds row (..+l16), 4 consecutive cols (quad*4+r)
  const bool doAct = (colBlk < act_cols);
  bf16* const Cp = doAct ? C1 : C2;
  const int cShift = doAct ? 0 : act_cols;
#pragma unroll
  for (int mi = 0; mi < 4; ++mi) {
    const int row = rowBlk + wr * 64 + mi * 16 + l16;
#pragma unroll
    for (int ni = 0; ni < 4; ++ni) {
      const int col0 = colBlk + wc * 64 + ni * 16 + quad * 4;
      const f32x4 bb = *(const f32x4*)(bias + col0);
      bf16x4 o;
#pragma unroll
      for (int r = 0; r < 4; ++r) {
        float x = acc[mi][ni][r] + bb[r];
        if (doAct) x = silu(x);
        o[r] = (bf16)x;
      }
      *(bf16x4*)(Cp + (size_t)row * ldc + (col0 - cShift)) = o;
    }
  }
}

// ---- value L2 + vW3 dot fused: efe += disc * silu(A@vW2+vb2) . vW3 ----
// grid (M/128, 8), block 256. No C output.
__global__ __launch_bounds__(256) void gemm_vdot(
    const bf16* __restrict__ A, const bf16* __restrict__ Bt,
    const float* __restrict__ vb2, const float* __restrict__ vW3,
    float* __restrict__ efe, float disc) {
  __shared__ alignas(16) bf16 As0[128 * 32], As1[128 * 32];
  __shared__ alignas(16) bf16 Bs0[128 * 32], Bs1[128 * 32];
  const int tid = threadIdx.x, wave = tid >> 6, lane = tid & 63;
  const int quad = lane >> 4, l16 = lane & 15;
  const int rowBlk = blockIdx.x * 128, colBlk = blockIdx.y * 128;
  const int wr = wave >> 1, wc = wave & 1;
  const int srow = lane >> 2, skel = (lane & 3) * 8;

  const bf16* gA0 = A + (size_t)(rowBlk + wave * 32 + srow) * 1024 + skel;
  const bf16* gA1 = gA0 + (size_t)16 * 1024;
  const bf16* gB0 = Bt + (size_t)(colBlk + wave * 32 + srow) * 1024 + skel;
  const bf16* gB1 = gB0 + (size_t)16 * 1024;
  bf16* const lA0 = As0 + wave * 32 * 32;
  bf16* const lA0b = As0 + (wave * 32 + 16) * 32;
  bf16* const lA1 = As1 + wave * 32 * 32;
  bf16* const lA1b = As1 + (wave * 32 + 16) * 32;
  bf16* const lB0 = Bs0 + wave * 32 * 32;
  bf16* const lB0b = Bs0 + (wave * 32 + 16) * 32;
  bf16* const lB1 = Bs1 + wave * 32 * 32;
  bf16* const lB1b = Bs1 + (wave * 32 + 16) * 32;

  f32x4 acc[4][4] = {};
  for (int k0 = 0; k0 < 1024; k0 += 64) {
    gld_lds16(gA0 + k0, lA0);
    gld_lds16(gA1 + k0, lA0b);
    gld_lds16(gA0 + k0 + 32, lA1);
    gld_lds16(gA1 + k0 + 32, lA1b);
    gld_lds16(gB0 + k0, lB0);
    gld_lds16(gB1 + k0, lB0b);
    gld_lds16(gB0 + k0 + 32, lB1);
    gld_lds16(gB1 + k0 + 32, lB1b);
    __syncthreads();
#pragma unroll
    for (int ks = 0; ks < 2; ++ks) {
      const bf16* aRd = (ks ? As1 : As0) + (wr * 64 + l16) * 32 + quad * 8;
      const bf16* bRd = (ks ? Bs1 : Bs0) + (wc * 64 + l16) * 32 + quad * 8;
      bf16x8 af[4], bfr[4];
#pragma unroll
      for (int i = 0; i < 4; ++i) {
        af[i] = *(const bf16x8*)(aRd + i * 16 * 32);
        bfr[i] = *(const bf16x8*)(bRd + i * 16 * 32);
      }
#pragma unroll
      for (int mi = 0; mi < 4; ++mi)
#pragma unroll
        for (int ni = 0; ni < 4; ++ni)
          acc[mi][ni] = MFMA16(bfr[ni], af[mi], acc[mi][ni]);
    }
    __syncthreads();
  }

#pragma unroll
  for (int mi = 0; mi < 4; ++mi) {
    const int row = rowBlk + wr * 64 + mi * 16 + l16;
    float p = 0.f;
#pragma unroll
    for (int ni = 0; ni < 4; ++ni) {
      const int col0 = colBlk + wc * 64 + ni * 16 + quad * 4;
      const f32x4 bb = *(const f32x4*)(vb2 + col0);
      const f32x4 w3 = *(const f32x4*)(vW3 + col0);
#pragma unroll
      for (int r = 0; r < 4; ++r) p += silu(acc[mi][ni][r] + bb[r]) * w3[r];
    }
    p += __shfl_xor(p, 16);
    p += __shfl_xor(p, 32);
    if (quad == 0) atomicAdd(efe + row, disc * p);
  }
}

// ---- dynamics L3 + z_next + KL partials fused -------------------------
// grid (M/64, 2), block 256: 64 rows x 128 cols per block, wave = 16 rows.
__global__ __launch_bounds__(256) void gemm_dyn3(
    const bf16* __restrict__ A, const bf16* __restrict__ Bt,
    const float* __restrict__ db3, float* __restrict__ Zf,
    bf16* __restrict__ Zb, float* __restrict__ s_n, float* __restrict__ s_c) {
  __shared__ alignas(16) bf16 As0[64 * 32], As1[64 * 32];
  __shared__ alignas(16) bf16 Bs0[128 * 32], Bs1[128 * 32];
  const int tid = threadIdx.x, wave = tid >> 6, lane = tid & 63;
  const int quad = lane >> 4, l16 = lane & 15;
  const int rowBlk = blockIdx.x * 64, colBlk = blockIdx.y * 128;
  const int srow = lane >> 2, skel = (lane & 3) * 8;

  const bf16* gA = A + (size_t)(rowBlk + wave * 16 + srow) * 1024 + skel;
  const bf16* gB0 = Bt + (size_t)(colBlk + wave * 32 + srow) * 1024 + skel;
  const bf16* gB1 = gB0 + (size_t)16 * 1024;
  bf16* const lA0 = As0 + wave * 16 * 32;
  bf16* const lA1 = As1 + wave * 16 * 32;
  bf16* const lB0 = Bs0 + wave * 32 * 32;
  bf16* const lB0b = Bs0 + (wave * 32 + 16) * 32;
  bf16* const lB1 = Bs1 + wave * 32 * 32;
  bf16* const lB1b = Bs1 + (wave * 32 + 16) * 32;

  f32x4 acc[8] = {};
  for (int k0 = 0; k0 < 1024; k0 += 64) {
    gld_lds16(gA + k0, lA0);
    gld_lds16(gA + k0 + 32, lA1);
    gld_lds16(gB0 + k0, lB0);
    gld_lds16(gB1 + k0, lB0b);
    gld_lds16(gB0 + k0 + 32, lB1);
    gld_lds16(gB1 + k0 + 32, lB1b);
    __syncthreads();
#pragma unroll
    for (int ks = 0; ks < 2; ++ks) {
      const bf16* aRd = (ks ? As1 : As0) + (wave * 16 + l16) * 32 + quad * 8;
      const bf16* bRd = (ks ? Bs1 : Bs0) + l16 * 32 + quad * 8;
      const bf16x8 af = *(const bf16x8*)aRd;
#pragma unroll
      for (int ni = 0; ni < 8; ++ni) {
        const bf16x8 bfr = *(const bf16x8*)(bRd + ni * 16 * 32);
        acc[ni] = MFMA16(bfr, af, acc[ni]);
      }
    }
    __syncthreads();
  }

  const int row = rowBlk + wave * 16 + l16;
  float pn = 0.f, pc = 0.f;
#pragma unroll
  for (int ni = 0; ni < 8; ++ni) {
    const int col0 = colBlk + ni * 16 + quad * 4;
    const f32x4 b4 = *(const f32x4*)(db3 + col0);
    float* zp = Zf + (size_t)row * 256 + col0;
    const f32x4 z = *(const f32x4*)zp;
    f32x4 zn;
    bf16x4 o;
#pragma unroll
    for (int r = 0; r < 4; ++r) {
      zn[r] = z[r] + acc[ni][r] + b4[r];
      pn += zn[r] * zn[r];
      pc += z[r] * zn[r];
      o[r] = (bf16)zn[r];
    }
    *(f32x4*)zp = zn;
    *(bf16x4*)(Zb + (size_t)row * 256 + col0) = o;
  }
  pn += __shfl_xor(pn, 16);
  pn += __shfl_xor(pn, 32);
  pc += __shfl_xor(pc, 16);
  pc += __shfl_xor(pc, 32);
  if (quad == 0) {
    atomicAdd(s_n + row, pn);
    atomicAdd(s_c + row, pc);
  }
}

// ---- KL epilogue: efe += disc*log1p(kl); roll ||z|| forward -----------
__global__ void kl_finish(float* __restrict__ s_z, float* __restrict__ s_n,
                          float* __restrict__ s_c, float* __restrict__ efe,
                          float disc) {
  const int m = blockIdx.x * 256 + threadIdx.x;  // grid 64
  const float sz = s_z[m], sn = s_n[m], sc = s_c[m];
  const float nz = sqrtf(sz) + 1e-8f, nn = sqrtf(sn) + 1e-8f;
  const float kl =
      0.5f * (sz / (nz * nz) + sn / (nn * nn) - 2.f * sc / (nz * nn));
  efe[m] += disc * log1pf(fmaxf(kl, 0.f));
  s_z[m] = sn;
  s_n[m] = 0.f;
  s_c[m] = 0.f;
}

// ---- heads + dynamics-L1 completion -----------------------------------
// grid (M/64), block 256. Stage 1: [mean|lstd] = H@Wt^T; action+entropy.
// Stage 2: Hd = silu(preD + action @ dW1a) (rank-32 MFMA per col-tile).
__global__ __launch_bounds__(256) void heads3(
    const bf16* __restrict__ H, const bf16* __restrict__ Wt,
    const float* __restrict__ pbm, const float* __restrict__ pbs,
    const float* __restrict__ noise, const bf16* __restrict__ preD,
    const bf16* __restrict__ dW1at, bf16* __restrict__ Hd,
    float* __restrict__ efe, int t, float disc) {
  __shared__ alignas(16) bf16 As0[64 * 32], As1[64 * 32];
  __shared__ alignas(16) bf16 Bs0[64 * 32], Bs1[64 * 32];
  __shared__ alignas(16) bf16 LAct[64 * 32];
  const int tid = threadIdx.x, wave = tid >> 6, lane = tid & 63;
  const int quad = lane >> 4, l16 = lane & 15;
  const int rowBlk = blockIdx.x * 64;
  const int srow = lane >> 2, skel = (lane & 3) * 8;

  const bf16* gA = H + (size_t)(rowBlk + wave * 16 + srow) * 1024 + skel;
  const bf16* gB = Wt + (size_t)(wave * 16 + srow) * 1024 + skel;
  bf16* const lA0 = As0 + wave * 16 * 32;
  bf16* const lA1 = As1 + wave * 16 * 32;
  bf16* const lB0 = Bs0 + wave * 16 * 32;
  bf16* const lB1 = Bs1 + wave * 16 * 32;

  f32x4 acc[4] = {};
  for (int k0 = 0; k0 < 1024; k0 += 64) {
    gld_lds16(gA + k0, lA0);
    gld_lds16(gA + k0 + 32, lA1);
    gld_lds16(gB + k0, lB0);
    gld_lds16(gB + k0 + 32, lB1);
    __syncthreads();
#pragma unroll
    for (int ks = 0; ks < 2; ++ks) {
      const bf16* aRd = (ks ? As1 : As0) + (wave * 16 + l16) * 32 + quad * 8;
      const bf16* bRd = (ks ? Bs1 : Bs0) + l16 * 32 + quad * 8;
      const bf16x8 af = *(const bf16x8*)aRd;
#pragma unroll
      for (int ni = 0; ni < 4; ++ni) {
        const bf16x8 bfr = *(const bf16x8*)(bRd + ni * 16 * 32);
        acc[ni] = MFMA16(bfr, af, acc[ni]);
      }
    }
    __syncthreads();
  }

  // action + entropy; lane holds cols {ni*16 + quad*4 + r} for ni 0..3,
  // where ni 0,1 = mean(0..31), ni 2,3 = log_std(0..31) for the same cols.
  const int row = rowBlk + wave * 16 + l16;
  const int n = row >> 10, b = row & 1023;
  float ent = 0.f;
#pragma unroll
  for (int ni = 0; ni < 2; ++ni) {
    const int col0 = ni * 16 + quad * 4;
    const f32x4 bm4 = *(const f32x4*)(pbm + col0);
    const f32x4 bs4 = *(const f32x4*)(pbs + col0);
    const f32x4 ep4 =
        *(const f32x4*)(noise + (((size_t)(n * 5 + t) * 1024 + b) * 32 + col0));
    bf16x4 o;
#pragma unroll
    for (int r = 0; r < 4; ++r) {
      const float mean = acc[ni][r] + bm4[r];
      float ls = acc[ni + 2][r] + bs4[r];
      ls = fminf(fmaxf(ls, -5.f), 2.f);
      o[r] = (bf16)(mean + __expf(ls) * ep4[r]);
      ent += ENT_C + ls;
    }
    *(bf16x4*)(LAct + (wave * 16 + l16) * 32 + col0) = o;
  }
  ent += __shfl_xor(ent, 16);
  ent += __shfl_xor(ent, 32);
  if (quad == 0) efe[row] += disc * (-0.1f) * ent;
  __syncthreads();  // LAct ready

  // rank-32 completion: Hd[row][c] = silu(preD[row][c] + act[row,:]·dW1a[:,c])
  const bf16x8 af2 = *(const bf16x8*)(LAct + (wave * 16 + l16) * 32 + quad * 8);
#pragma unroll 4
  for (int ct = 0; ct < 64; ++ct) {
    const bf16x8 wf = *(const bf16x8*)(dW1at + (size_t)(ct * 16 + l16) * 32 + quad * 8);
    f32x4 a = {};
    a = MFMA16(wf, af2, a);
    const int col0 = ct * 16 + quad * 4;
    const bf16x4 pd = *(const bf16x4*)(preD + (size_t)row * 1024 + col0);
    bf16x4 o;
#pragma unroll
    for (int r = 0; r < 4; ++r) o[r] = (bf16)silu(a[r] + (float)pd[r]);
    *(bf16x4*)(Hd + (size_t)row * 1024 + col0) = o;
  }
}

// ---- setup kernels ----------------------------------------------------
__global__ void transpose_bf16(const float* __restrict__ in,
                               bf16* __restrict__ out, int K, int N, int ldin) {
  const int idx = blockIdx.x * 256 + threadIdx.x;
  if (idx >= K * N) return;
  const int n = idx / K, k = idx - n * K;
  out[idx] = (bf16)in[(size_t)k * ldin + n];
}

// pdW1t [2048][256] = [pW1^T ; dW1z^T]; pdb1 [2048] = [pb1 | db1]
__global__ void build_pd1(const float* __restrict__ pW1,
                          const float* __restrict__ dW1,
                          const float* __restrict__ pb1,
                          const float* __restrict__ db1,
                          bf16* __restrict__ Wt, float* __restrict__ bias) {
  const int idx = blockIdx.x * 256 + threadIdx.x;  // 2048*256
  const int n = idx >> 8, k = idx & 255;
  Wt[idx] = (bf16)(n < 1024 ? pW1[(size_t)k * 1024 + n]
                            : dW1[(size_t)k * 1024 + (n - 1024)]);
  if (idx < 2048) bias[idx] = idx < 1024 ? pb1[idx] : db1[idx - 1024];
}

// dW1at [1024][32]: action part of dW1, transposed
__global__ void build_dW1at(const float* __restrict__ dW1,
                            bf16* __restrict__ out) {
  const int idx = blockIdx.x * 256 + threadIdx.x;  // 1024*32
  const int n = idx >> 5, k = idx & 31;
  out[idx] = (bf16)dW1[(size_t)(256 + k) * 1024 + n];
}

__global__ void combine_heads(const float* __restrict__ pWm,
                              const float* __restrict__ pWs,
                              bf16* __restrict__ out) {
  const int idx = blockIdx.x * 256 + threadIdx.x;  // 64*1024
  const int n = idx >> 10, k = idx & 1023;
  const float v = (n < 32) ? pWm[k * 32 + n] : pWs[k * 32 + (n - 32)];
  out[idx] = (bf16)v;
}

__global__ void make_vbias(const float* __restrict__ vW1,
                           const float* __restrict__ vb1,
                           float* __restrict__ vbias) {
  const int idx = blockIdx.x * 256 + threadIdx.x;
  if (idx >= 5 * 1024) return;
  const int t = idx >> 10, j = idx & 1023;
  float s = vb1[j];
  const float lt = (float)t;
  for (int i = 0; i < 64; ++i) {
    const float f = expf(-9.210340371976184f * (float)i / 64.f);
    const float ang = lt * f;
    s += sinf(ang) * vW1[(size_t)(256 + i) * 1024 + j];
    s += cosf(ang) * vW1[(size_t)(256 + 64 + i) * 1024 + j];
  }
  vbias[idx] = s;
}

// one block per row: replicate latent, row norm^2, zero accumulators
__global__ void init_state2(const float* __restrict__ latent,
                            float* __restrict__ Zf, bf16* __restrict__ Zb,
                            float* __restrict__ efe, float* __restrict__ s_z,
                            float* __restrict__ s_n, float* __restrict__ s_c) {
  __shared__ float red[4];
  const int m = blockIdx.x, c = threadIdx.x;
  const float z = latent[(size_t)(m & 1023) * 256 + c];
  Zf[(size_t)m * 256 + c] = z;
  Zb[(size_t)m * 256 + c] = (bf16)z;
  float v = z * z;
#pragma unroll
  for (int msk = 1; msk < 64; msk <<= 1) v += __shfl_xor(v, msk);
  if ((c & 63) == 0) red[c >> 6] = v;
  __syncthreads();
  if (c == 0) {
    s_z[m] = red[0] + red[1] + red[2] + red[3];
    s_n[m] = 0.f;
    s_c[m] = 0.f;
    efe[m] = 0.f;
  }
}

__global__ void finalize(const float* __restrict__ efe,
                         const float* __restrict__ vb3,
                         float* __restrict__ out) {
  const int b = blockIdx.x * 256 + threadIdx.x;  // 1024
  float s = 0.f;
#pragma unroll
  for (int n = 0; n < 16; ++n) s += efe[n * 1024 + b];
  out[b] = s * (1.f / 16.f) + SUMDISC * vb3[0];
}

extern "C" void kernel_launch(void* const* d_in, const int* in_sizes, int n_in,
                              void* d_out, int out_size, void* d_ws,
                              size_t ws_size, hipStream_t stream) {
  const float* latent = (const float*)d_in[0];
  const float* noise = (const float*)d_in[1];
  const float* pW1 = (const float*)d_in[2];
  const float* pb1 = (const float*)d_in[3];
  const float* pW2 = (const float*)d_in[4];
  const float* pb2 = (const float*)d_in[5];
  const float* pWm = (const float*)d_in[6];
  const float* pbm = (const float*)d_in[7];
  const float* pWs = (const float*)d_in[8];
  const float* pbs = (const float*)d_in[9];
  const float* dW1 = (const float*)d_in[10];
  const float* db1 = (const float*)d_in[11];
  const float* dW2 = (const float*)d_in[12];
  const float* db2 = (const float*)d_in[13];
  const float* dW3 = (const float*)d_in[14];
  const float* db3 = (const float*)d_in[15];
  const float* vW1 = (const float*)d_in[16];
  const float* vb1 = (const float*)d_in[17];
  const float* vW2 = (const float*)d_in[18];
  const float* vb2 = (const float*)d_in[19];
  const float* vW3 = (const float*)d_in[20];
  const float* vb3 = (const float*)d_in[21];

  char* w = (char*)d_ws;
  size_t off = 0;
  auto take = [&](size_t bytes) -> void* {
    void* p = (void*)(w + off);
    off = (off + bytes + 255) & ~(size_t)255;
    return p;
  };
  bf16* pdW1t = (bf16*)take(2048ull * 256 * 2);   // [2048][256]
  float* pdb1 = (float*)take(2048ull * 4);
  bf16* pW2t = (bf16*)take(1024ull * 1024 * 2);
  bf16* pHt = (bf16*)take(64ull * 1024 * 2);
  bf16* dW1at = (bf16*)take(1024ull * 32 * 2);
  bf16* dW2t = (bf16*)take(1024ull * 1024 * 2);
  bf16* dW3t = (bf16*)take(256ull * 1024 * 2);
  bf16* vW1t = (bf16*)take(1024ull * 256 * 2);
  bf16* vW2t = (bf16*)take(1024ull * 1024 * 2);
  float* vbias = (float*)take(5ull * 1024 * 4);
  bf16* Zb = (bf16*)take((size_t)MR * 256 * 2);   // [M][256] bf16 z
  float* Zf = (float*)take((size_t)MR * 256 * 4); // fp32 master z
  bf16* Ha = (bf16*)take((size_t)MR * 1024 * 2);
  bf16* Hc = (bf16*)take((size_t)MR * 1024 * 2);
  bf16* Hp = (bf16*)take((size_t)MR * 1024 * 2);  // preD
  float* efe = (float*)take((size_t)MR * 4);
  float* s_z = (float*)take((size_t)MR * 4);
  float* s_n = (float*)take((size_t)MR * 4);
  float* s_c = (float*)take((size_t)MR * 4);

  const dim3 blk(256);
  const int BIG = 1 << 30;
  build_pd1<<<dim3(2048 * 256 / 256), blk, 0, stream>>>(pW1, dW1, pb1, db1, pdW1t, pdb1);
  transpose_bf16<<<dim3(1024 * 1024 / 256), blk, 0, stream>>>(pW2, pW2t, 1024, 1024, 1024);
  combine_heads<<<dim3(64 * 1024 / 256), blk, 0, stream>>>(pWm, pWs, pHt);
  build_dW1at<<<dim3(1024 * 32 / 256), blk, 0, stream>>>(dW1, dW1at);
  transpose_bf16<<<dim3(1024 * 1024 / 256), blk, 0, stream>>>(dW2, dW2t, 1024, 1024, 1024);
  transpose_bf16<<<dim3(1024 * 256 / 256), blk, 0, stream>>>(dW3, dW3t, 1024, 256, 256);
  transpose_bf16<<<dim3(256 * 1024 / 256), blk, 0, stream>>>(vW1, vW1t, 256, 1024, 1024);
  transpose_bf16<<<dim3(1024 * 1024 / 256), blk, 0, stream>>>(vW2, vW2t, 1024, 1024, 1024);
  make_vbias<<<dim3(20), blk, 0, stream>>>(vW1, vb1, vbias);
  init_state2<<<dim3(MR), blk, 0, stream>>>(latent, Zf, Zb, efe, s_z, s_n, s_c);

  float disc = 1.f;
  for (int t = 0; t < HORIZON; ++t) {
    // [policy L1 | dynamics L1 z-part]: cols<1024 -> silu -> Ha; else -> Hp
    gemm128<<<dim3(128, 16), blk, 0, stream>>>(Zb, 256, 256, pdW1t, pdb1, 1024,
                                               Ha, Hp, 1024);
    // policy L2: Ha -> Hc
    gemm128<<<dim3(128, 8), blk, 0, stream>>>(Ha, 1024, 1024, pW2t, pb2, BIG,
                                              Hc, Hc, 1024);
    // heads + dyn-L1 completion: Hc,Hp -> action/entropy, Hd -> Ha
    heads3<<<dim3(MR / 64), blk, 0, stream>>>(Hc, pHt, pbm, pbs, noise, Hp,
                                              dW1at, Ha, efe, t, disc);
    // dynamics L2: Ha -> Hc
    gemm128<<<dim3(128, 8), blk, 0, stream>>>(Ha, 1024, 1024, dW2t, db2, BIG,
                                              Hc, Hc, 1024);
    // dynamics L3 fused with z_next/KL partials
    gemm_dyn3<<<dim3(MR / 64, 2), blk, 0, stream>>>(Hc, dW3t, db3, Zf, Zb, s_n,
                                                    s_c);
    kl_finish<<<dim3(MR / 256), blk, 0, stream>>>(s_z, s_n, s_c, efe, disc);
    // value L1 on z_next (time embed folded into vbias[t]): Zb -> Ha
    gemm128<<<dim3(128, 8), blk, 0, stream>>>(Zb, 256, 256, vW1t, vbias + t * 1024,
                                              BIG, Ha, Ha, 1024);
    // value L2 + vW3 dot -> efe
    gemm_vdot<<<dim3(128, 8), blk, 0, stream>>>(Ha, vW2t, vb2, vW3, efe, disc);
    disc *= 0.99f;
  }
  finalize<<<dim3(4), blk, 0, stream>>>(efe, vb3, (float*)d_out);
}

// Round 4
// 1548.165 us; speedup vs baseline: 1.1716x; 1.0842x over previous
//
#include <hip/hip_runtime.h>
#include <cstdint>
#include <cstddef>
#include <cmath>

// DiffusionActiveInference on MI355X (gfx950).
// R4: (1) t=0 trunk at M=1024 (shared latent across 16 trajectories; heads
// reads shared rows via row mask); (2) value network deferred + batched in
// 2-step chunks (M=32768), output aliasing dead Ha/Hc; (3) KL batched into
// one end-of-loop kernel. GEMM core unchanged from R3 (BK=64 dual panels).

typedef __bf16 bf16;
typedef __attribute__((ext_vector_type(8))) __bf16 bf16x8;
typedef __attribute__((ext_vector_type(4))) __bf16 bf16x4;
typedef __attribute__((ext_vector_type(4))) float f32x4;

static constexpr int BATCH = 1024, NTRAJ = 16, HORIZON = 5;
static constexpr int MR = NTRAJ * BATCH;  // 16384 GEMM rows
static constexpr float ENT_C = 1.4189385332046727f;  // 0.5*(1+log(2*pi))
static constexpr float SUMDISC = 4.90099501f;        // sum 0.99^t, t=0..4

// ---- async global->LDS, 16B per lane ----------------------------------
__device__ __forceinline__ void gld_lds16(const bf16* g, const bf16* l) {
  typedef __attribute__((address_space(1))) const uint32_t gq_t;
  typedef __attribute__((address_space(3))) uint32_t lq_t;
  gq_t* gp = (gq_t*)(uintptr_t)g;
  lq_t* lp = (lq_t*)(uint32_t)(uintptr_t)l;
  __builtin_amdgcn_global_load_lds(gp, lp, 16, 0, 0);
}

__device__ __forceinline__ float silu(float x) {
  return x / (1.f + __expf(-x));
}

#define MFMA16(a, b, c) __builtin_amdgcn_mfma_f32_16x16x32_bf16((a), (b), (c), 0, 0, 0)

// ---- generic GEMM: C = maybe_silu(A[M,K](lda) @ Bt[N,K]^T + bias) -----
// grid (M/128, N/128), block 256. BK=64 as two BK=32 panels.
// silu iff colBlk < act_cols; output to C1 if colBlk < act_cols else C2 at
// (col - act_cols). BROW: bias += (rowBlk>>14)<<10 (per-16384-row bias set).
template <int BROW>
__global__ __launch_bounds__(256) void gemm128(
    const bf16* __restrict__ A, int lda, int K, const bf16* __restrict__ Bt,
    const float* __restrict__ bias, int act_cols,
    bf16* __restrict__ C1, bf16* __restrict__ C2, int ldc) {
  __shared__ alignas(16) bf16 As0[128 * 32], As1[128 * 32];
  __shared__ alignas(16) bf16 Bs0[128 * 32], Bs1[128 * 32];
  const int tid = threadIdx.x, wave = tid >> 6, lane = tid & 63;
  const int quad = lane >> 4, l16 = lane & 15;
  const int rowBlk = blockIdx.x * 128, colBlk = blockIdx.y * 128;
  const int wr = wave >> 1, wc = wave & 1;
  const int srow = lane >> 2, skel = (lane & 3) * 8;

  const bf16* gA0 = A + (size_t)(rowBlk + wave * 32 + srow) * lda + skel;
  const bf16* gA1 = gA0 + (size_t)16 * lda;
  const bf16* gB0 = Bt + (size_t)(colBlk + wave * 32 + srow) * K + skel;
  const bf16* gB1 = gB0 + (size_t)16 * K;
  bf16* const lA0 = As0 + wave * 32 * 32;
  bf16* const lA0b = As0 + (wave * 32 + 16) * 32;
  bf16* const lA1 = As1 + wave * 32 * 32;
  bf16* const lA1b = As1 + (wave * 32 + 16) * 32;
  bf16* const lB0 = Bs0 + wave * 32 * 32;
  bf16* const lB0b = Bs0 + (wave * 32 + 16) * 32;
  bf16* const lB1 = Bs1 + wave * 32 * 32;
  bf16* const lB1b = Bs1 + (wave * 32 + 16) * 32;

  f32x4 acc[4][4] = {};
  for (int k0 = 0; k0 < K; k0 += 64) {
    gld_lds16(gA0 + k0, lA0);
    gld_lds16(gA1 + k0, lA0b);
    gld_lds16(gA0 + k0 + 32, lA1);
    gld_lds16(gA1 + k0 + 32, lA1b);
    gld_lds16(gB0 + k0, lB0);
    gld_lds16(gB1 + k0, lB0b);
    gld_lds16(gB0 + k0 + 32, lB1);
    gld_lds16(gB1 + k0 + 32, lB1b);
    __syncthreads();
#pragma unroll
    for (int ks = 0; ks < 2; ++ks) {
      const bf16* aRd = (ks ? As1 : As0) + (wr * 64 + l16) * 32 + quad * 8;
      const bf16* bRd = (ks ? Bs1 : Bs0) + (wc * 64 + l16) * 32 + quad * 8;
      bf16x8 af[4], bfr[4];
#pragma unroll
      for (int i = 0; i < 4; ++i) {
        af[i] = *(const bf16x8*)(aRd + i * 16 * 32);
        bfr[i] = *(const bf16x8*)(bRd + i * 16 * 32);
      }
#pragma unroll
      for (int mi = 0; mi < 4; ++mi)
#pragma unroll
        for (int ni = 0; ni < 4; ++ni)
          acc[mi][ni] = MFMA16(bfr[ni], af[mi], acc[mi][ni]);
    }
    __syncthreads();
  }

  const float* bp = bias + (BROW ? ((rowBlk >> 14) << 10) : 0);
  const bool doAct = (colBlk < act_cols);
  bf16* const Cp = doAct ? C1 : C2;
  const int cShift = doAct ? 0 : act_cols;
#pragma unroll
  for (int mi = 0; mi < 4; ++mi) {
    const int row = rowBlk + wr * 64 + mi * 16 + l16;
#pragma unroll
    for (int ni = 0; ni < 4; ++ni) {
      const int col0 = colBlk + wc * 64 + ni * 16 + quad * 4;
      const f32x4 bb = *(const f32x4*)(bp + col0);
      bf16x4 o;
#pragma unroll
      for (int r = 0; r < 4; ++r) {
        float x = acc[mi][ni][r] + bb[r];
        if (doAct) x = silu(x);
        o[r] = (bf16)x;
      }
      *(bf16x4*)(Cp + (size_t)row * ldc + (col0 - cShift)) = o;
    }
  }
}

// ---- value L2 + vW3 dot fused, multi-step batch -----------------------
// grid (M/128, 8). Row block rowBlk>>14 selects step (disc); efe index
// is row & (MR-1). No C output.
__global__ __launch_bounds__(256) void gemm_vdot(
    const bf16* __restrict__ A, const bf16* __restrict__ Bt,
    const float* __restrict__ vb2, const float* __restrict__ vW3,
    float* __restrict__ efe, int t0) {
  __shared__ alignas(16) bf16 As0[128 * 32], As1[128 * 32];
  __shared__ alignas(16) bf16 Bs0[128 * 32], Bs1[128 * 32];
  const int tid = threadIdx.x, wave = tid >> 6, lane = tid & 63;
  const int quad = lane >> 4, l16 = lane & 15;
  const int rowBlk = blockIdx.x * 128, colBlk = blockIdx.y * 128;
  const int wr = wave >> 1, wc = wave & 1;
  const int srow = lane >> 2, skel = (lane & 3) * 8;

  const bf16* gA0 = A + (size_t)(rowBlk + wave * 32 + srow) * 1024 + skel;
  const bf16* gA1 = gA0 + (size_t)16 * 1024;
  const bf16* gB0 = Bt + (size_t)(colBlk + wave * 32 + srow) * 1024 + skel;
  const bf16* gB1 = gB0 + (size_t)16 * 1024;
  bf16* const lA0 = As0 + wave * 32 * 32;
  bf16* const lA0b = As0 + (wave * 32 + 16) * 32;
  bf16* const lA1 = As1 + wave * 32 * 32;
  bf16* const lA1b = As1 + (wave * 32 + 16) * 32;
  bf16* const lB0 = Bs0 + wave * 32 * 32;
  bf16* const lB0b = Bs0 + (wave * 32 + 16) * 32;
  bf16* const lB1 = Bs1 + wave * 32 * 32;
  bf16* const lB1b = Bs1 + (wave * 32 + 16) * 32;

  f32x4 acc[4][4] = {};
  for (int k0 = 0; k0 < 1024; k0 += 64) {
    gld_lds16(gA0 + k0, lA0);
    gld_lds16(gA1 + k0, lA0b);
    gld_lds16(gA0 + k0 + 32, lA1);
    gld_lds16(gA1 + k0 + 32, lA1b);
    gld_lds16(gB0 + k0, lB0);
    gld_lds16(gB1 + k0, lB0b);
    gld_lds16(gB0 + k0 + 32, lB1);
    gld_lds16(gB1 + k0 + 32, lB1b);
    __syncthreads();
#pragma unroll
    for (int ks = 0; ks < 2; ++ks) {
      const bf16* aRd = (ks ? As1 : As0) + (wr * 64 + l16) * 32 + quad * 8;
      const bf16* bRd = (ks ? Bs1 : Bs0) + (wc * 64 + l16) * 32 + quad * 8;
      bf16x8 af[4], bfr[4];
#pragma unroll
      for (int i = 0; i < 4; ++i) {
        af[i] = *(const bf16x8*)(aRd + i * 16 * 32);
        bfr[i] = *(const bf16x8*)(bRd + i * 16 * 32);
      }
#pragma unroll
      for (int mi = 0; mi < 4; ++mi)
#pragma unroll
        for (int ni = 0; ni < 4; ++ni)
          acc[mi][ni] = MFMA16(bfr[ni], af[mi], acc[mi][ni]);
    }
    __syncthreads();
  }

  const int tt = t0 + (rowBlk >> 14);
  float disc = 1.f;
  for (int i = 0; i < tt; ++i) disc *= 0.99f;
#pragma unroll
  for (int mi = 0; mi < 4; ++mi) {
    const int row = rowBlk + wr * 64 + mi * 16 + l16;
    float p = 0.f;
#pragma unroll
    for (int ni = 0; ni < 4; ++ni) {
      const int col0 = colBlk + wc * 64 + ni * 16 + quad * 4;
      const f32x4 bb = *(const f32x4*)(vb2 + col0);
      const f32x4 w3 = *(const f32x4*)(vW3 + col0);
#pragma unroll
      for (int r = 0; r < 4; ++r) p += silu(acc[mi][ni][r] + bb[r]) * w3[r];
    }
    p += __shfl_xor(p, 16);
    p += __shfl_xor(p, 32);
    if (quad == 0) atomicAdd(efe + (row & (MR - 1)), disc * p);
  }
}

// ---- dynamics L3 + z_next + KL partials fused -------------------------
// grid (M/64, 2), block 256: 64 rows x 128 cols per block, wave = 16 rows.
__global__ __launch_bounds__(256) void gemm_dyn3(
    const bf16* __restrict__ A, const bf16* __restrict__ Bt,
    const float* __restrict__ db3, float* __restrict__ Zf,
    bf16* __restrict__ Zb, float* __restrict__ s_n, float* __restrict__ s_c) {
  __shared__ alignas(16) bf16 As0[64 * 32], As1[64 * 32];
  __shared__ alignas(16) bf16 Bs0[128 * 32], Bs1[128 * 32];
  const int tid = threadIdx.x, wave = tid >> 6, lane = tid & 63;
  const int quad = lane >> 4, l16 = lane & 15;
  const int rowBlk = blockIdx.x * 64, colBlk = blockIdx.y * 128;
  const int srow = lane >> 2, skel = (lane & 3) * 8;

  const bf16* gA = A + (size_t)(rowBlk + wave * 16 + srow) * 1024 + skel;
  const bf16* gB0 = Bt + (size_t)(colBlk + wave * 32 + srow) * 1024 + skel;
  const bf16* gB1 = gB0 + (size_t)16 * 1024;
  bf16* const lA0 = As0 + wave * 16 * 32;
  bf16* const lA1 = As1 + wave * 16 * 32;
  bf16* const lB0 = Bs0 + wave * 32 * 32;
  bf16* const lB0b = Bs0 + (wave * 32 + 16) * 32;
  bf16* const lB1 = Bs1 + wave * 32 * 32;
  bf16* const lB1b = Bs1 + (wave * 32 + 16) * 32;

  f32x4 acc[8] = {};
  for (int k0 = 0; k0 < 1024; k0 += 64) {
    gld_lds16(gA + k0, lA0);
    gld_lds16(gA + k0 + 32, lA1);
    gld_lds16(gB0 + k0, lB0);
    gld_lds16(gB1 + k0, lB0b);
    gld_lds16(gB0 + k0 + 32, lB1);
    gld_lds16(gB1 + k0 + 32, lB1b);
    __syncthreads();
#pragma unroll
    for (int ks = 0; ks < 2; ++ks) {
      const bf16* aRd = (ks ? As1 : As0) + (wave * 16 + l16) * 32 + quad * 8;
      const bf16* bRd = (ks ? Bs1 : Bs0) + l16 * 32 + quad * 8;
      const bf16x8 af = *(const bf16x8*)aRd;
#pragma unroll
      for (int ni = 0; ni < 8; ++ni) {
        const bf16x8 bfr = *(const bf16x8*)(bRd + ni * 16 * 32);
        acc[ni] = MFMA16(bfr, af, acc[ni]);
      }
    }
    __syncthreads();
  }

  const int row = rowBlk + wave * 16 + l16;
  float pn = 0.f, pc = 0.f;
#pragma unroll
  for (int ni = 0; ni < 8; ++ni) {
    const int col0 = colBlk + ni * 16 + quad * 4;
    const f32x4 b4 = *(const f32x4*)(db3 + col0);
    float* zp = Zf + (size_t)row * 256 + col0;
    const f32x4 z = *(const f32x4*)zp;
    f32x4 zn;
    bf16x4 o;
#pragma unroll
    for (int r = 0; r < 4; ++r) {
      zn[r] = z[r] + acc[ni][r] + b4[r];
      pn += zn[r] * zn[r];
      pc += z[r] * zn[r];
      o[r] = (bf16)zn[r];
    }
    *(f32x4*)zp = zn;
    *(bf16x4*)(Zb + (size_t)row * 256 + col0) = o;
  }
  pn += __shfl_xor(pn, 16);
  pn += __shfl_xor(pn, 32);
  pc += __shfl_xor(pc, 16);
  pc += __shfl_xor(pc, 32);
  if (quad == 0) {
    atomicAdd(s_n + row, pn);
    atomicAdd(s_c + row, pc);
  }
}

// ---- batched KL epilogue: all 5 steps at once -------------------------
// grid (MR/256). ||z_{t+1}||^2 = s_n of step t (rolls forward).
__global__ void kl_batch(const float* __restrict__ sz0,
                         const float* __restrict__ snAll,
                         const float* __restrict__ scAll,
                         float* __restrict__ efe) {
  const int m = blockIdx.x * 256 + threadIdx.x;
  float sz = sz0[m];
  float disc = 1.f, acc = 0.f;
  for (int t = 0; t < HORIZON; ++t) {
    const float sn = snAll[t * MR + m], sc = scAll[t * MR + m];
    const float nz = sqrtf(sz) + 1e-8f, nn = sqrtf(sn) + 1e-8f;
    const float kl =
        0.5f * (sz / (nz * nz) + sn / (nn * nn) - 2.f * sc / (nz * nn));
    acc += disc * log1pf(fmaxf(kl, 0.f));
    sz = sn;
    disc *= 0.99f;
  }
  efe[m] += acc;
}

// ---- heads + dynamics-L1 completion -----------------------------------
// grid (M/64), block 256. rmask: H/preD row mask (1023 at t=0, else ~0).
__global__ __launch_bounds__(256) void heads3(
    const bf16* __restrict__ H, const bf16* __restrict__ Wt,
    const float* __restrict__ pbm, const float* __restrict__ pbs,
    const float* __restrict__ noise, const bf16* __restrict__ preD,
    const bf16* __restrict__ dW1at, bf16* __restrict__ Hd,
    float* __restrict__ efe, int t, float disc, int rmask) {
  __shared__ alignas(16) bf16 As0[64 * 32], As1[64 * 32];
  __shared__ alignas(16) bf16 Bs0[64 * 32], Bs1[64 * 32];
  __shared__ alignas(16) bf16 LAct[64 * 32];
  const int tid = threadIdx.x, wave = tid >> 6, lane = tid & 63;
  const int quad = lane >> 4, l16 = lane & 15;
  const int rowBlk = blockIdx.x * 64;
  const int srow = lane >> 2, skel = (lane & 3) * 8;

  const bf16* gA =
      H + (size_t)((rowBlk + wave * 16 + srow) & rmask) * 1024 + skel;
  const bf16* gB = Wt + (size_t)(wave * 16 + srow) * 1024 + skel;
  bf16* const lA0 = As0 + wave * 16 * 32;
  bf16* const lA1 = As1 + wave * 16 * 32;
  bf16* const lB0 = Bs0 + wave * 16 * 32;
  bf16* const lB1 = Bs1 + wave * 16 * 32;

  f32x4 acc[4] = {};
  for (int k0 = 0; k0 < 1024; k0 += 64) {
    gld_lds16(gA + k0, lA0);
    gld_lds16(gA + k0 + 32, lA1);
    gld_lds16(gB + k0, lB0);
    gld_lds16(gB + k0 + 32, lB1);
    __syncthreads();
#pragma unroll
    for (int ks = 0; ks < 2; ++ks) {
      const bf16* aRd = (ks ? As1 : As0) + (wave * 16 + l16) * 32 + quad * 8;
      const bf16* bRd = (ks ? Bs1 : Bs0) + l16 * 32 + quad * 8;
      const bf16x8 af = *(const bf16x8*)aRd;
#pragma unroll
      for (int ni = 0; ni < 4; ++ni) {
        const bf16x8 bfr = *(const bf16x8*)(bRd + ni * 16 * 32);
        acc[ni] = MFMA16(bfr, af, acc[ni]);
      }
    }
    __syncthreads();
  }

  const int row = rowBlk + wave * 16 + l16;
  const int n = row >> 10, b = row & 1023;
  float ent = 0.f;
#pragma unroll
  for (int ni = 0; ni < 2; ++ni) {
    const int col0 = ni * 16 + quad * 4;
    const f32x4 bm4 = *(const f32x4*)(pbm + col0);
    const f32x4 bs4 = *(const f32x4*)(pbs + col0);
    const f32x4 ep4 =
        *(const f32x4*)(noise + (((size_t)(n * 5 + t) * 1024 + b) * 32 + col0));
    bf16x4 o;
#pragma unroll
    for (int r = 0; r < 4; ++r) {
      const float mean = acc[ni][r] + bm4[r];
      float ls = acc[ni + 2][r] + bs4[r];
      ls = fminf(fmaxf(ls, -5.f), 2.f);
      o[r] = (bf16)(mean + __expf(ls) * ep4[r]);
      ent += ENT_C + ls;
    }
    *(bf16x4*)(LAct + (wave * 16 + l16) * 32 + col0) = o;
  }
  ent += __shfl_xor(ent, 16);
  ent += __shfl_xor(ent, 32);
  if (quad == 0) efe[row] += disc * (-0.1f) * ent;
  __syncthreads();  // LAct ready

  // rank-32 completion: Hd[row][c] = silu(preD[row][c] + act[row,:]·dW1a[:,c])
  const int prow = row & rmask;
  const bf16x8 af2 = *(const bf16x8*)(LAct + (wave * 16 + l16) * 32 + quad * 8);
#pragma unroll 4
  for (int ct = 0; ct < 64; ++ct) {
    const bf16x8 wf =
        *(const bf16x8*)(dW1at + (size_t)(ct * 16 + l16) * 32 + quad * 8);
    f32x4 a = {};
    a = MFMA16(wf, af2, a);
    const int col0 = ct * 16 + quad * 4;
    const bf16x4 pd = *(const bf16x4*)(preD + (size_t)prow * 1024 + col0);
    bf16x4 o;
#pragma unroll
    for (int r = 0; r < 4; ++r) o[r] = (bf16)silu(a[r] + (float)pd[r]);
    *(bf16x4*)(Hd + (size_t)row * 1024 + col0) = o;
  }
}

// ---- setup kernels ----------------------------------------------------
__global__ void transpose_bf16(const float* __restrict__ in,
                               bf16* __restrict__ out, int K, int N, int ldin) {
  const int idx = blockIdx.x * 256 + threadIdx.x;
  if (idx >= K * N) return;
  const int n = idx / K, k = idx - n * K;
  out[idx] = (bf16)in[(size_t)k * ldin + n];
}

__global__ void build_pd1(const float* __restrict__ pW1,
                          const float* __restrict__ dW1,
                          const float* __restrict__ pb1,
                          const float* __restrict__ db1,
                          bf16* __restrict__ Wt, float* __restrict__ bias) {
  const int idx = blockIdx.x * 256 + threadIdx.x;  // 2048*256
  const int n = idx >> 8, k = idx & 255;
  Wt[idx] = (bf16)(n < 1024 ? pW1[(size_t)k * 1024 + n]
                            : dW1[(size_t)k * 1024 + (n - 1024)]);
  if (idx < 2048) bias[idx] = idx < 1024 ? pb1[idx] : db1[idx - 1024];
}

__global__ void build_dW1at(const float* __restrict__ dW1,
                            bf16* __restrict__ out) {
  const int idx = blockIdx.x * 256 + threadIdx.x;  // 1024*32
  const int n = idx >> 5, k = idx & 31;
  out[idx] = (bf16)dW1[(size_t)(256 + k) * 1024 + n];
}

__global__ void combine_heads(const float* __restrict__ pWm,
                              const float* __restrict__ pWs,
                              bf16* __restrict__ out) {
  const int idx = blockIdx.x * 256 + threadIdx.x;  // 64*1024
  const int n = idx >> 10, k = idx & 1023;
  const float v = (n < 32) ? pWm[k * 32 + n] : pWs[k * 32 + (n - 32)];
  out[idx] = (bf16)v;
}

__global__ void make_vbias(const float* __restrict__ vW1,
                           const float* __restrict__ vb1,
                           float* __restrict__ vbias) {
  const int idx = blockIdx.x * 256 + threadIdx.x;
  if (idx >= 5 * 1024) return;
  const int t = idx >> 10, j = idx & 1023;
  float s = vb1[j];
  const float lt = (float)t;
  for (int i = 0; i < 64; ++i) {
    const float f = expf(-9.210340371976184f * (float)i / 64.f);
    const float ang = lt * f;
    s += sinf(ang) * vW1[(size_t)(256 + i) * 1024 + j];
    s += cosf(ang) * vW1[(size_t)(256 + 64 + i) * 1024 + j];
  }
  vbias[idx] = s;
}

// one block per row m: Zf replicated, Zb0 (first 1024 rows), sz0, zeros
__global__ void init_state3(const float* __restrict__ latent,
                            float* __restrict__ Zf, bf16* __restrict__ Zb0,
                            float* __restrict__ efe, float* __restrict__ sz0,
                            float* __restrict__ snAll,
                            float* __restrict__ scAll) {
  __shared__ float red[4];
  const int m = blockIdx.x, c = threadIdx.x;
  const float z = latent[(size_t)(m & 1023) * 256 + c];
  Zf[(size_t)m * 256 + c] = z;
  if (m < 1024) Zb0[(size_t)m * 256 + c] = (bf16)z;
  float v = z * z;
#pragma unroll
  for (int msk = 1; msk < 64; msk <<= 1) v += __shfl_xor(v, msk);
  if ((c & 63) == 0) red[c >> 6] = v;
  __syncthreads();
  if (c < HORIZON) {
    snAll[c * MR + m] = 0.f;
    scAll[c * MR + m] = 0.f;
  }
  if (c == 0) {
    sz0[m] = red[0] + red[1] + red[2] + red[3];
    efe[m] = 0.f;
  }
}

__global__ void finalize(const float* __restrict__ efe,
                         const float* __restrict__ vb3,
                         float* __restrict__ out) {
  const int b = blockIdx.x * 256 + threadIdx.x;  // 1024
  float s = 0.f;
#pragma unroll
  for (int n = 0; n < 16; ++n) s += efe[n * 1024 + b];
  out[b] = s * (1.f / 16.f) + SUMDISC * vb3[0];
}

extern "C" void kernel_launch(void* const* d_in, const int* in_sizes, int n_in,
                              void* d_out, int out_size, void* d_ws,
                              size_t ws_size, hipStream_t stream) {
  const float* latent = (const float*)d_in[0];
  const float* noise = (const float*)d_in[1];
  const float* pW1 = (const float*)d_in[2];
  const float* pb1 = (const float*)d_in[3];
  const float* pW2 = (const float*)d_in[4];
  const float* pb2 = (const float*)d_in[5];
  const float* pWm = (const float*)d_in[6];
  const float* pbm = (const float*)d_in[7];
  const float* pWs = (const float*)d_in[8];
  const float* pbs = (const float*)d_in[9];
  const float* dW1 = (const float*)d_in[10];
  const float* db1 = (const float*)d_in[11];
  const float* dW2 = (const float*)d_in[12];
  const float* db2 = (const float*)d_in[13];
  const float* dW3 = (const float*)d_in[14];
  const float* db3 = (const float*)d_in[15];
  const float* vW1 = (const float*)d_in[16];
  const float* vb1 = (const float*)d_in[17];
  const float* vW2 = (const float*)d_in[18];
  const float* vb2 = (const float*)d_in[19];
  const float* vW3 = (const float*)d_in[20];
  const float* vb3 = (const float*)d_in[21];

  char* w = (char*)d_ws;
  size_t off = 0;
  auto take = [&](size_t bytes) -> void* {
    void* p = (void*)(w + off);
    off = (off + bytes + 255) & ~(size_t)255;
    return p;
  };
  bf16* pdW1t = (bf16*)take(2048ull * 256 * 2);
  float* pdb1 = (float*)take(2048ull * 4);
  bf16* pW2t = (bf16*)take(1024ull * 1024 * 2);
  bf16* pHt = (bf16*)take(64ull * 1024 * 2);
  bf16* dW1at = (bf16*)take(1024ull * 32 * 2);
  bf16* dW2t = (bf16*)take(1024ull * 1024 * 2);
  bf16* dW3t = (bf16*)take(256ull * 1024 * 2);
  bf16* vW1t = (bf16*)take(1024ull * 256 * 2);
  bf16* vW2t = (bf16*)take(1024ull * 1024 * 2);
  float* vbias = (float*)take(5ull * 1024 * 4);
  bf16* Zb0 = (bf16*)take(1024ull * 256 * 2);      // z0 bf16, shared rows
  bf16* Zall = (bf16*)take(5ull * MR * 256 * 2);   // z_next per step
  float* Zf = (float*)take((size_t)MR * 256 * 4);  // fp32 master z
  float* efe = (float*)take((size_t)MR * 4);
  float* sz0 = (float*)take((size_t)MR * 4);
  float* snAll = (float*)take(5ull * MR * 4);
  float* scAll = (float*)take(5ull * MR * 4);
  // Ha/Hc/Hp contiguous; value batch output aliases Ha+Hc (both dead then)
  bf16* Ha = (bf16*)take((size_t)MR * 1024 * 2);
  bf16* Hc = (bf16*)take((size_t)MR * 1024 * 2);
  bf16* Hp = (bf16*)take((size_t)MR * 1024 * 2);
  bf16* Vc = Ha;  // [2*MR][1024] alias for value chunks

  const dim3 blk(256);
  const int BIG = 1 << 30;
  build_pd1<<<dim3(2048 * 256 / 256), blk, 0, stream>>>(pW1, dW1, pb1, db1, pdW1t, pdb1);
  transpose_bf16<<<dim3(1024 * 1024 / 256), blk, 0, stream>>>(pW2, pW2t, 1024, 1024, 1024);
  combine_heads<<<dim3(64 * 1024 / 256), blk, 0, stream>>>(pWm, pWs, pHt);
  build_dW1at<<<dim3(1024 * 32 / 256), blk, 0, stream>>>(dW1, dW1at);
  transpose_bf16<<<dim3(1024 * 1024 / 256), blk, 0, stream>>>(dW2, dW2t, 1024, 1024, 1024);
  transpose_bf16<<<dim3(1024 * 256 / 256), blk, 0, stream>>>(dW3, dW3t, 1024, 256, 256);
  transpose_bf16<<<dim3(256 * 1024 / 256), blk, 0, stream>>>(vW1, vW1t, 256, 1024, 1024);
  transpose_bf16<<<dim3(1024 * 1024 / 256), blk, 0, stream>>>(vW2, vW2t, 1024, 1024, 1024);
  make_vbias<<<dim3(20), blk, 0, stream>>>(vW1, vb1, vbias);
  init_state3<<<dim3(MR), blk, 0, stream>>>(latent, Zf, Zb0, efe, sz0, snAll, scAll);

  float disc = 1.f;
  for (int t = 0; t < HORIZON; ++t) {
    const bf16* Zprev = (t == 0) ? Zb0 : Zall + (size_t)(t - 1) * MR * 256;
    const int mBlks = (t == 0) ? 8 : 128;  // t=0: shared latent, M=1024
    const int rmask = (t == 0) ? 1023 : 0x7FFFFFFF;
    // [policy L1 | dynamics L1 z-part]: cols<1024 -> silu -> Ha; else -> Hp
    gemm128<0><<<dim3(mBlks, 16), blk, 0, stream>>>(Zprev, 256, 256, pdW1t,
                                                    pdb1, 1024, Ha, Hp, 1024);
    // policy L2: Ha -> Hc
    gemm128<0><<<dim3(mBlks, 8), blk, 0, stream>>>(Ha, 1024, 1024, pW2t, pb2,
                                                   BIG, Hc, Hc, 1024);
    // heads + dyn-L1 completion: Hc,Hp (masked rows) -> action/ent, Hd -> Ha
    heads3<<<dim3(MR / 64), blk, 0, stream>>>(Hc, pHt, pbm, pbs, noise, Hp,
                                              dW1at, Ha, efe, t, disc, rmask);
    // dynamics L2: Ha -> Hc
    gemm128<0><<<dim3(128, 8), blk, 0, stream>>>(Ha, 1024, 1024, dW2t, db2,
                                                 BIG, Hc, Hc, 1024);
    // dynamics L3 fused with z_next / KL partials
    gemm_dyn3<<<dim3(MR / 64, 2), blk, 0, stream>>>(
        Hc, dW3t, db3, Zf, Zall + (size_t)t * MR * 256, snAll + (size_t)t * MR,
        scAll + (size_t)t * MR);
    disc *= 0.99f;
  }

  // batched KL over all steps
  kl_batch<<<dim3(MR / 256), blk, 0, stream>>>(sz0, snAll, scAll, efe);

  // deferred value network in 2-step chunks (output aliases dead Ha/Hc)
  for (int t0 = 0; t0 < HORIZON; t0 += 2) {
    const int steps = (t0 + 2 <= HORIZON) ? 2 : 1;
    const int mBlks = steps * (MR / 128);
    // value L1 (silu, per-step bias via BROW): Zall[t0..] -> Vc
    gemm128<1><<<dim3(mBlks, 8), blk, 0, stream>>>(
        Zall + (size_t)t0 * MR * 256, 256, 256, vW1t, vbias + t0 * 1024, BIG,
        Vc, Vc, 1024);
    // value L2 + vW3 dot -> efe (disc per row chunk)
    gemm_vdot<<<dim3(mBlks, 8), blk, 0, stream>>>(Vc, vW2t, vb2, vW3, efe, t0);
  }
  finalize<<<dim3(4), blk, 0, stream>>>(efe, vb3, (float*)d_out);
}